// Round 14
// baseline (867.644 us; speedup 1.0000x reference)
//
#include <hip/hip_runtime.h>
#include <hip/hip_fp16.h>
#include <stdint.h>

// MUL=128, Z=10, L_DIMS=(1,3,5,7) offs (0,1,4,9), MM_DIMS=(1,3)

__device__ __forceinline__ float silu_f(float x) {
  return x / (1.0f + __expf(-x));
}

union F2H2 { float f; __half2 h; };

typedef _Float16 hv2 __attribute__((ext_vector_type(2)));
union FHV { float f; hv2 h; };

#if defined(__has_builtin)
#if __has_builtin(__builtin_amdgcn_fdot2)
#define HAS_FDOT2 1
#endif
#endif

// wn = sum_{z=0..9} ar[z] * wr[z] with both sides fp16 pairs
__device__ __forceinline__ float wn_dot(const hv2* ar, const hv2* wr) {
#ifdef HAS_FDOT2
  float s = 0.f;
#pragma unroll
  for (int z = 0; z < 5; z++) s = __builtin_amdgcn_fdot2(ar[z], wr[z], s, false);
  return s;
#else
  float s = 0.f;
#pragma unroll
  for (int z = 0; z < 5; z++)
    s += (float)ar[z][0] * (float)wr[z][0] + (float)ar[z][1] * (float)wr[z][1];
  return s;
#endif
}

__global__ void k_zero_int(int* p, int n) {
  int i = blockIdx.x * blockDim.x + threadIdx.x;
  if (i < n) p[i] = 0;
}

// Mc = M1@M2@M3@M4 / 2048  (linear MLP collapse), Mc is [16,256]
__global__ __launch_bounds__(256) void k_prep(
    const float* __restrict__ M1, const float* __restrict__ M2,
    const float* __restrict__ M3, const float* __restrict__ M4,
    float* __restrict__ Mc) {
  __shared__ float T1[16 * 64];
  __shared__ float T2[16 * 64];
  int t = threadIdx.x;
  for (int i = t; i < 16 * 64; i += 256) {
    int r = i >> 6, c = i & 63;
    float s = 0.f;
    for (int k = 0; k < 64; k++) s += M1[r * 64 + k] * M2[k * 64 + c];
    T1[i] = s;
  }
  __syncthreads();
  for (int i = t; i < 16 * 64; i += 256) {
    int r = i >> 6, c = i & 63;
    float s = 0.f;
    for (int k = 0; k < 64; k++) s += T1[r * 64 + k] * M3[k * 64 + c];
    T2[i] = s;
  }
  __syncthreads();
  for (int i = t; i < 16 * 256; i += 256) {
    int r = i >> 8, c = i & 255;
    float s = 0.f;
    for (int k = 0; k < 64; k++) s += T2[r * 64 + k] * M4[k * 256 + c];
    Mc[i] = s * (1.0f / 2048.0f);
  }
}

// x = node_feats @ W_up / sqrt(128)   one block per node, 128 threads
__global__ __launch_bounds__(128) void k_up(const float* __restrict__ nf,
                                            const float* __restrict__ W,
                                            float* __restrict__ x, int Nn) {
  int n = blockIdx.x;
  int v = threadIdx.x;
  __shared__ float row[128];
  row[v] = nf[n * 128 + v];
  __syncthreads();
  float s = 0.f;
#pragma unroll 8
  for (int k = 0; k < 128; k++) s += row[k] * W[k * 128 + v];
  x[n * 128 + v] = s * 0.08838834764831845f;
}

__global__ void k_count(const int* __restrict__ recv, int* __restrict__ deg, int E) {
  int e = blockIdx.x * blockDim.x + threadIdx.x;
  if (e < E) atomicAdd(&deg[recv[e]], 1);
}

// exclusive scan of deg -> rowstart[0..N], cursor copy. single block 1024 threads.
__global__ __launch_bounds__(1024) void k_scan(const int* __restrict__ deg,
                                               int* __restrict__ rowstart,
                                               int* __restrict__ cursor, int Nn) {
  __shared__ int part[1024];
  int t = threadIdx.x;
  int chunk = (Nn + 1023) / 1024;
  int lo = t * chunk;
  int hi = lo + chunk; if (hi > Nn) hi = Nn; if (lo > Nn) lo = Nn;
  int s = 0;
  for (int i = lo; i < hi; i++) s += deg[i];
  part[t] = s;
  __syncthreads();
  for (int o = 1; o < 1024; o <<= 1) {
    int v = (t >= o) ? part[t - o] : 0;
    __syncthreads();
    part[t] += v;
    __syncthreads();
  }
  int base = (t == 0) ? 0 : part[t - 1];
  for (int i = lo; i < hi; i++) {
    rowstart[i] = base;
    cursor[i] = base;
    base += deg[i];
  }
  if (t == 1023) rowstart[Nn] = part[1023];
}

__global__ void k_fill(const int* __restrict__ recv, int* __restrict__ cursor,
                       int* __restrict__ elist, int E) {
  int e = blockIdx.x * blockDim.x + threadIdx.x;
  if (e < E) {
    int p = atomicAdd(&cursor[recv[e]], 1);
    elist[p] = e;
  }
}

// ---------------- edge kernel: MLP + W4 GEMM (+ optional Mc GEMM) -----------
// w4e[e][512] half, layout [l*128+u], pre-scaled *0.125 (fp32 accum, single
// rounding). If wmme != nullptr: wmme[e][256] half, layout [j*128+u]
// (fp32 accum from ef, single rounding). dens[e] = tanh(q^2).
__global__ __launch_bounds__(256) void k_edge_w4(
    const float* __restrict__ edge_feats, const float* __restrict__ mminv,
    const int* __restrict__ sender,
    const float* __restrict__ W1, const float* __restrict__ W2,
    const float* __restrict__ W3, const float* __restrict__ W4,
    const float* __restrict__ Mc, const float* __restrict__ Wd,
    __half* __restrict__ w4e, __half* __restrict__ wmme,
    float* __restrict__ dens, int E) {
  const int base = blockIdx.x * 8;
  const int t = threadIdx.x;
  __shared__ float ef[8][16];
  __shared__ float hA[8][64];
  __shared__ float hB[8][64];
  __shared__ float w4s[8][512];
  const int gwave = t >> 6;
  const int o6 = t & 63;

  if (t < 128) {
    int g = t >> 4, j = t & 15;
    int e = base + g;
    float v = 0.f;
    if (e < E) v = (j < 8) ? edge_feats[e * 8 + j] : mminv[sender[e] * 8 + (j - 8)];
    ef[g][j] = v;
  } else if (t < 136) {
    int g = t - 128;
    int e = base + g;
    if (e < E) {
      float q = 0.f;
#pragma unroll
      for (int k = 0; k < 8; k++) q += edge_feats[e * 8 + k] * Wd[k];
      q *= 0.35355339059327373f;
      dens[e] = tanhf(q * q);
    }
  }
  __syncthreads();

#pragma unroll
  for (int rep = 0; rep < 2; rep++) {
    int g = gwave + rep * 4;
    float s = 0.f;
#pragma unroll
    for (int k = 0; k < 16; k++) s += ef[g][k] * W1[k * 64 + o6];
    hA[g][o6] = silu_f(s * 0.25f);
  }
#pragma unroll
  for (int rep = 0; rep < 2; rep++) {
    int g = gwave + rep * 4;
    float s = 0.f;
#pragma unroll 8
    for (int k = 0; k < 64; k++) s += hA[g][k] * W2[k * 64 + o6];
    hB[g][o6] = silu_f(s * 0.125f);
  }
#pragma unroll
  for (int rep = 0; rep < 2; rep++) {
    int g = gwave + rep * 4;
    float s = 0.f;
#pragma unroll 8
    for (int k = 0; k < 64; k++) s += hB[g][k] * W3[k * 64 + o6];
    hA[g][o6] = silu_f(s * 0.125f);
  }
  __syncthreads();  // hA visible cross-wave

  {
    float a[8] = {0, 0, 0, 0, 0, 0, 0, 0};
    float b[8] = {0, 0, 0, 0, 0, 0, 0, 0};
#pragma unroll 8
    for (int k = 0; k < 64; k++) {
      float w0 = W4[k * 512 + t];
      float w1 = W4[k * 512 + t + 256];
#pragma unroll
      for (int g = 0; g < 8; g++) {
        float h = hA[g][k];
        a[g] += h * w0;
        b[g] += h * w1;
      }
    }
    int p0 = (t & 3) * 128 + (t >> 2);
    int p1 = (t & 3) * 128 + 64 + (t >> 2);
#pragma unroll
    for (int g = 0; g < 8; g++) {
      w4s[g][p0] = a[g] * 0.125f;
      w4s[g][p1] = b[g] * 0.125f;
    }
  }
  __syncthreads();  // w4s visible

  __half2* dst = (__half2*)w4e;
#pragma unroll
  for (int g = 0; g < 8; g++) {
    int e = base + g;
    if (e < E) {
      dst[(size_t)e * 256 + t] =
          __halves2half2(__float2half(w4s[g][2 * t]), __float2half(w4s[g][2 * t + 1]));
    }
  }

  // optional Mc GEMM (ef still intact): thread t owns column t of [8,256]
  if (wmme != nullptr) {
    float c[8] = {0, 0, 0, 0, 0, 0, 0, 0};
#pragma unroll
    for (int k = 0; k < 16; k++) {
      float w = Mc[k * 256 + t];
#pragma unroll
      for (int g = 0; g < 8; g++) c[g] += ef[g][k] * w;
    }
    const int pm = (t & 1) * 128 + (t >> 1);
#pragma unroll
    for (int g = 0; g < 8; g++) {
      int e = base + g;
      if (e < E) wmme[(size_t)e * 256 + pm] = __float2half(c[g]);
    }
  }
}

// ---------------- mode 0 gather: conv only (w4e + wmme precomputed) ---------
// 2 barriers/chunk, ~5.5 KB LDS. Edge ids captured to regs between barriers
// B and C (writers pass next-iter B before rewriting eS -> race-free).
__global__ __launch_bounds__(256) void k_gather_c2(
    const float* __restrict__ x, const float* __restrict__ edge_attrs,
    const float* __restrict__ mmattrs, const int* __restrict__ sender,
    const __half* __restrict__ w4e, const __half* __restrict__ wmme,
    const float* __restrict__ dens,
    const int* __restrict__ rowstart, const int* __restrict__ elist,
    float* __restrict__ msg, float* __restrict__ mmr, float* __restrict__ densN,
    int Nn) {
  const int n = blockIdx.x;
  const int t = threadIdx.x;
  const int start = rowstart[n], end = rowstart[n + 1];

  __shared__ float xjs[8][128];
  __shared__ float shs[8][16];
  __shared__ float mmshs[8][4];
  __shared__ float denss[8];
  __shared__ int eS[8], sS[8];

  float accm[8] = {0, 0, 0, 0, 0, 0, 0, 0};
  float accmm0 = 0.f, accmm1 = 0.f;
  float accd = 0.f;

  const int u = t & 127;
  const int half = t >> 7;  // wave-uniform

  for (int base = start; base < end; base += 8) {
    if (t < 8) {
      int g = t;
      if (base + g < end) {
        int e = elist[base + g];
        eS[g] = e;
        sS[g] = sender[e];
        denss[g] = dens[e];
      } else {
        eS[g] = -1;
        sS[g] = 0;
        denss[g] = 0.f;
      }
    }
    __syncthreads();  // B: eS/sS/denss visible
    int erA[8];
#pragma unroll
    for (int g = 0; g < 8; g++) {
      int ev = eS[g];
      erA[g] = ev < 0 ? 0 : ev;
    }
    if (t < 128) {
      int g = t >> 4, j = t & 15;
      shs[g][j] = (eS[g] >= 0) ? edge_attrs[eS[g] * 16 + j] : 0.f;
    } else if (t < 160) {
      int g = (t - 128) >> 2, j = (t - 128) & 3;
      mmshs[g][j] = (eS[g] >= 0) ? mmattrs[sS[g] * 4 + j] : 0.f;
    }
    for (int i = t; i < 1024; i += 256) {
      int g = i >> 7, uu = i & 127;
      xjs[g][uu] = (eS[g] >= 0) ? x[(size_t)sS[g] * 128 + uu] : 0.f;
    }
    __syncthreads();  // C: staged data visible

#pragma unroll 2
    for (int g = 0; g < 8; g++) {
      const __half* w4g = w4e + (size_t)erA[g] * 512;
      const __half* wmg = wmme + (size_t)erA[g] * 256;
      float w40 = __half2float(w4g[u]);
      float w41 = __half2float(w4g[128 + u]);
      float w42 = __half2float(w4g[256 + u]);
      float w43 = __half2float(w4g[384 + u]);
      float wm0 = __half2float(wmg[u]);
      float wm1 = __half2float(wmg[128 + u]);
      float xj = xjs[g][u];
      float sh0 = shs[g][0];
      float pre0 = w40 * xj * sh0;
      float wg0 = wm0 * pre0;
      float wg1 = wm1 * pre0;
      float mm0 = wg0 * xj * mmshs[g][0];
      float m1 = wg1 * xj;
      float bx = mm0 * xj;
      float b0 = w40 * bx, b1 = w41 * bx, b2 = w42 * bx, b3 = w43 * bx;
      if (half == 0) {
        accmm0 += mm0;
        accmm1 += m1 * mmshs[g][1];
        accm[0] += b0 * sh0;
        accm[1] += b1 * shs[g][1];
        accm[2] += b1 * shs[g][2];
        accm[3] += b1 * shs[g][3];
        accm[4] += b2 * shs[g][4];
        accm[5] += b2 * shs[g][5];
        accm[6] += b2 * shs[g][6];
        accm[7] += b2 * shs[g][7];
      } else {
        accmm0 += m1 * mmshs[g][2];
        accmm1 += m1 * mmshs[g][3];
        accm[0] += b2 * shs[g][8];
        accm[1] += b3 * shs[g][9];
        accm[2] += b3 * shs[g][10];
        accm[3] += b3 * shs[g][11];
        accm[4] += b3 * shs[g][12];
        accm[5] += b3 * shs[g][13];
        accm[6] += b3 * shs[g][14];
        accm[7] += b3 * shs[g][15];
      }
    }
    if (t == 0) {
#pragma unroll
      for (int g = 0; g < 8; g++) accd += denss[g];  // same wave as writers
    }
  }

  float4* mp = (float4*)(msg + (size_t)n * 2048 + u * 16 + half * 8);
  mp[0] = make_float4(accm[0], accm[1], accm[2], accm[3]);
  mp[1] = make_float4(accm[4], accm[5], accm[6], accm[7]);
  *(float2*)(mmr + (size_t)n * 512 + u * 4 + half * 2) = make_float2(accmm0, accmm1);
  if (t == 0) densN[n] = accd;
}

// ---------------- mode 1 gather: w4e precomputed, Mc in-loop (round-12) -----
__global__ __launch_bounds__(256) void k_gather_c(
    const float* __restrict__ x, const float* __restrict__ edge_attrs,
    const float* __restrict__ edge_feats, const float* __restrict__ mminv,
    const float* __restrict__ mmattrs, const int* __restrict__ sender,
    const float* __restrict__ Mc, const __half* __restrict__ w4e,
    const float* __restrict__ dens,
    const int* __restrict__ rowstart, const int* __restrict__ elist,
    float* __restrict__ msg, float* __restrict__ mmr, float* __restrict__ densN,
    int Nn) {
  const int n = blockIdx.x;
  const int t = threadIdx.x;
  const int start = rowstart[n], end = rowstart[n + 1];

  __shared__ float ef[8][16];
  __shared__ float wmms[8][256];
  __shared__ float xjs[8][128];
  __shared__ float shs[8][16];
  __shared__ float mmshs[8][4];
  __shared__ float denss[8];
  __shared__ int eS[8], sS[8];

  float accm[8] = {0, 0, 0, 0, 0, 0, 0, 0};
  float accmm0 = 0.f, accmm1 = 0.f;
  float accd = 0.f;

  const int u = t & 127;
  const int half = t >> 7;  // wave-uniform

  for (int base = start; base < end; base += 8) {
    if (t < 8) {
      int g = t;
      if (base + g < end) {
        int e = elist[base + g];
        eS[g] = e;
        sS[g] = sender[e];
        denss[g] = dens[e];
      } else {
        eS[g] = -1;
        sS[g] = 0;
        denss[g] = 0.f;
      }
    }
    __syncthreads();  // B: eS/sS/denss visible
    int erA[8];
#pragma unroll
    for (int g = 0; g < 8; g++) {
      int ev = eS[g];
      erA[g] = ev < 0 ? 0 : ev;
    }
    if (t < 128) {
      int g = t >> 4, j = t & 15;
      int e = eS[g];
      shs[g][j] = (e >= 0) ? edge_attrs[e * 16 + j] : 0.f;
      float v = 0.f;
      if (e >= 0) v = (j < 8) ? edge_feats[e * 8 + j] : mminv[sS[g] * 8 + (j - 8)];
      ef[g][j] = v;
    } else if (t < 160) {
      int g = (t - 128) >> 2, j = (t - 128) & 3;
      mmshs[g][j] = (eS[g] >= 0) ? mmattrs[sS[g] * 4 + j] : 0.f;
    }
    for (int i = t; i < 1024; i += 256) {
      int g = i >> 7, uu = i & 127;
      xjs[g][uu] = (eS[g] >= 0) ? x[(size_t)sS[g] * 128 + uu] : 0.f;
    }
    __syncthreads();  // C: staged data visible

    {
      float c[8] = {0, 0, 0, 0, 0, 0, 0, 0};
#pragma unroll
      for (int k = 0; k < 16; k++) {
        float w = Mc[k * 256 + t];
#pragma unroll
        for (int g = 0; g < 8; g++) c[g] += ef[g][k] * w;
      }
      int p = (t & 1) * 128 + (t >> 1);
#pragma unroll
      for (int g = 0; g < 8; g++) wmms[g][p] = c[g];
    }
    __syncthreads();  // E: wmms visible

#pragma unroll 2
    for (int g = 0; g < 8; g++) {
      const __half* w4g = w4e + (size_t)erA[g] * 512;
      float w40 = __half2float(w4g[u]);
      float w41 = __half2float(w4g[128 + u]);
      float w42 = __half2float(w4g[256 + u]);
      float w43 = __half2float(w4g[384 + u]);
      float wm0 = wmms[g][u];
      float wm1 = wmms[g][128 + u];
      float xj = xjs[g][u];
      float sh0 = shs[g][0];
      float pre0 = w40 * xj * sh0;
      float wg0 = wm0 * pre0;
      float wg1 = wm1 * pre0;
      float mm0 = wg0 * xj * mmshs[g][0];
      float m1 = wg1 * xj;
      float bx = mm0 * xj;
      float b0 = w40 * bx, b1 = w41 * bx, b2 = w42 * bx, b3 = w43 * bx;
      if (half == 0) {
        accmm0 += mm0;
        accmm1 += m1 * mmshs[g][1];
        accm[0] += b0 * sh0;
        accm[1] += b1 * shs[g][1];
        accm[2] += b1 * shs[g][2];
        accm[3] += b1 * shs[g][3];
        accm[4] += b2 * shs[g][4];
        accm[5] += b2 * shs[g][5];
        accm[6] += b2 * shs[g][6];
        accm[7] += b2 * shs[g][7];
      } else {
        accmm0 += m1 * mmshs[g][2];
        accmm1 += m1 * mmshs[g][3];
        accm[0] += b2 * shs[g][8];
        accm[1] += b3 * shs[g][9];
        accm[2] += b3 * shs[g][10];
        accm[3] += b3 * shs[g][11];
        accm[4] += b3 * shs[g][12];
        accm[5] += b3 * shs[g][13];
        accm[6] += b3 * shs[g][14];
        accm[7] += b3 * shs[g][15];
      }
    }
    if (t == 0) {
#pragma unroll
      for (int g = 0; g < 8; g++) accd += denss[g];
    }
  }

  float4* mp = (float4*)(msg + (size_t)n * 2048 + u * 16 + half * 8);
  mp[0] = make_float4(accm[0], accm[1], accm[2], accm[3]);
  mp[1] = make_float4(accm[4], accm[5], accm[6], accm[7]);
  *(float2*)(mmr + (size_t)n * 512 + u * 4 + half * 2) = make_float2(accmm0, accmm1);
  if (t == 0) densN[n] = accd;
}

// zero out2 blocks l=2,3 (no path -> zero)
__global__ void k_zero2(float* __restrict__ out2, int Nn) {
  int i = blockIdx.x * blockDim.x + threadIdx.x;
  if (i < Nn * 128) {
    float4 z = make_float4(0.f, 0.f, 0.f, 0.f);
    float4* p = (float4*)(out2 + (size_t)i * 16);
    p[1] = z;
    p[2] = z;
    p[3] = z;
  }
}

// ---------------- Wt pre-transpose (fp16) -----------------------------------
__global__ __launch_bounds__(128) void k_wt(const float* __restrict__ Wskip,
                                            const float* __restrict__ Wmskip,
                                            __half* __restrict__ Wt) {
  int bx = blockIdx.x;              // 0..767 : L = bx>>7, u = bx&127
  int L = bx >> 7, u = bx & 127;
  int v = threadIdx.x;
  const float* src = (L < 4) ? (Wskip + (size_t)L * 163840)
                             : (Wmskip + (size_t)(L - 4) * 163840);
  __half* dst = Wt + (((size_t)L * 128 + u) * 128 + v) * 12;
#pragma unroll
  for (int z = 0; z < 10; z++) dst[z] = __float2half(src[u * 1280 + z * 128 + v]);
  dst[10] = __float2half(0.f);
  dst[11] = __float2half(0.f);
}

// ---------------- merged per-l linear + skip TP, 8-node tiles (round 12) ----
template <int D, int SP>
__device__ __forceinline__ void skip2_body(
    const float* __restrict__ attrs, const float* __restrict__ in, int in_rs,
    int in_us, int in_cb, const float* __restrict__ Wl,
    const float* __restrict__ densN, float basescl, bool useDinv,
    const __half* __restrict__ Wt, float* __restrict__ outp, int out_cb,
    int Nn, int n0, float* lin_s, float (*attrs_s)[10]) {
  const int t = threadIdx.x;
  for (int i = t; i < 80; i += 256) {
    int nn = i / 10, z = i - nn * 10;
    int n = n0 + nn;
    attrs_s[nn][z] = (n < Nn) ? attrs[n * 10 + z] : 0.f;
  }
  // zero-padded staging: full SP per slot (pads = 0 so vector math is inert)
  for (int i = t; i < 8 * 128 * SP; i += 256) {
    int nn = i / (128 * SP);
    int r = i - nn * 128 * SP;
    int uu = r / SP;
    int m = r - uu * SP;
    int n = n0 + nn;
    lin_s[i] = (n < Nn && m < D) ? in[(size_t)n * in_rs + uu * in_us + in_cb + m] : 0.f;
  }
  __syncthreads();

  const int v = t & 127, hf = t >> 7;  // hf handles nodes hf*4+q, q=0..3
  constexpr int NV = (SP + 3) / 4;

  // ---- phase 1: per-l channel mix ----
  if constexpr (SP == 1) {
    float lm[4] = {0, 0, 0, 0};
    for (int uu = 0; uu < 128; uu++) {
      float wv = Wl[uu * 128 + v];
#pragma unroll
      for (int q = 0; q < 4; q++) lm[q] += lin_s[(hf * 4 + q) * 128 + uu] * wv;
    }
    __syncthreads();
#pragma unroll
    for (int q = 0; q < 4; q++) {
      int nd = n0 + hf * 4 + q;
      float scl = basescl;
      if (useDinv) scl *= 1.0f / (((nd < Nn) ? densN[nd] : 0.f) + 1.0f);
      lin_s[(hf * 4 + q) * 128 + v] = lm[q] * scl;
    }
    __syncthreads();
  } else {
    float4 lmv[4][NV];
#pragma unroll
    for (int q = 0; q < 4; q++)
#pragma unroll
      for (int iv = 0; iv < NV; iv++) lmv[q][iv] = make_float4(0.f, 0.f, 0.f, 0.f);
    for (int uu = 0; uu < 128; uu++) {
      float wv = Wl[uu * 128 + v];
#pragma unroll
      for (int q = 0; q < 4; q++) {
        const float4* ls4 = (const float4*)&lin_s[((hf * 4 + q) * 128 + uu) * SP];
#pragma unroll
        for (int iv = 0; iv < NV; iv++) {
          float4 lv = ls4[iv];
          lmv[q][iv].x += lv.x * wv;
          lmv[q][iv].y += lv.y * wv;
          lmv[q][iv].z += lv.z * wv;
          lmv[q][iv].w += lv.w * wv;
        }
      }
    }
    __syncthreads();
#pragma unroll
    for (int q = 0; q < 4; q++) {
      int nd = n0 + hf * 4 + q;
      float scl = basescl;
      if (useDinv) scl *= 1.0f / (((nd < Nn) ? densN[nd] : 0.f) + 1.0f);
      float4* d4 = (float4*)&lin_s[((hf * 4 + q) * 128 + v) * SP];
#pragma unroll
      for (int iv = 0; iv < NV; iv++) {
        float4 o = lmv[q][iv];
        o.x *= scl; o.y *= scl; o.z *= scl; o.w *= scl;
        d4[iv] = o;  // pads: 0*scl = 0
      }
    }
    __syncthreads();
  }

  // ---- phase 2: skip tensor product ----
  hv2 ah[4][5];
#pragma unroll
  for (int q = 0; q < 4; q++)
#pragma unroll
    for (int z2 = 0; z2 < 5; z2++) {
      hv2 a;
      a[0] = (_Float16)attrs_s[hf * 4 + q][2 * z2];
      a[1] = (_Float16)attrs_s[hf * 4 + q][2 * z2 + 1];
      ah[q][z2] = a;
    }

  const __half* wp0 = Wt + (size_t)v * 12;

  if constexpr (SP == 1) {
    float acc[4] = {0, 0, 0, 0};
    for (int u = 0; u < 128; u++) {
      const float2* fp = (const float2*)(wp0 + (size_t)u * 1536);
      float2 q0 = fp[0], q1 = fp[1], q2 = fp[2];
      FHV c0, c1, c2, c3, c4;
      c0.f = q0.x; c1.f = q0.y; c2.f = q1.x; c3.f = q1.y; c4.f = q2.x;
      hv2 wr[5] = {c0.h, c1.h, c2.h, c3.h, c4.h};
#pragma unroll
      for (int q = 0; q < 4; q++) {
        float wn = wn_dot(ah[q], wr);
        acc[q] += lin_s[(hf * 4 + q) * 128 + u] * wn;
      }
    }
#pragma unroll
    for (int q = 0; q < 4; q++) {
      int n = n0 + hf * 4 + q;
      if (n < Nn) outp[(size_t)n * 2048 + v * 16 + out_cb] = acc[q] * 0.027950849718747371f;
    }
  } else {
    float4 accv[4][NV];
#pragma unroll
    for (int q = 0; q < 4; q++)
#pragma unroll
      for (int iv = 0; iv < NV; iv++) accv[q][iv] = make_float4(0.f, 0.f, 0.f, 0.f);
    for (int u = 0; u < 128; u++) {
      const float2* fp = (const float2*)(wp0 + (size_t)u * 1536);
      float2 q0 = fp[0], q1 = fp[1], q2 = fp[2];
      FHV c0, c1, c2, c3, c4;
      c0.f = q0.x; c1.f = q0.y; c2.f = q1.x; c3.f = q1.y; c4.f = q2.x;
      hv2 wr[5] = {c0.h, c1.h, c2.h, c3.h, c4.h};
#pragma unroll
      for (int q = 0; q < 4; q++) {
        float wn = wn_dot(ah[q], wr);
        const float4* ls4 = (const float4*)&lin_s[((hf * 4 + q) * 128 + u) * SP];
#pragma unroll
        for (int iv = 0; iv < NV; iv++) {
          float4 lv = ls4[iv];
          accv[q][iv].x += lv.x * wn;
          accv[q][iv].y += lv.y * wn;
          accv[q][iv].z += lv.z * wn;
          accv[q][iv].w += lv.w * wn;
        }
      }
    }
#pragma unroll
    for (int q = 0; q < 4; q++) {
      int n = n0 + hf * 4 + q;
      if (n < Nn) {
        float* op = outp + (size_t)n * 2048 + v * 16 + out_cb;
        const float* af = (const float*)&accv[q][0];
#pragma unroll
        for (int m = 0; m < D; m++) op[m] = af[m] * 0.027950849718747371f;
      }
    }
  }
}

__global__ __launch_bounds__(256) void k_skip2(
    const float* __restrict__ attrs, const float* __restrict__ msg,
    const float* __restrict__ mmr, const float* __restrict__ densN,
    const float* __restrict__ Wlin, const float* __restrict__ Wmlin,
    const __half* __restrict__ Wt, float* __restrict__ out, int Nn) {
  __shared__ float lin_s[8 * 128 * 8];
  __shared__ float attrs_s[8][10];
  const int n0 = blockIdx.x * 8;
  const int job = blockIdx.y;
  const __half* Wtj = Wt + (size_t)job * 128 * 128 * 12;
  const float scl = 0.08838834764831845f;
  const float sm = 0.08838834764831845f / 20.0f;
  switch (job) {
    case 0: skip2_body<1, 1>(attrs, msg, 2048, 16, 0, Wlin, densN, scl, true, Wtj, out, 0, Nn, n0, lin_s, attrs_s); break;
    case 1: skip2_body<3, 4>(attrs, msg, 2048, 16, 1, Wlin + 16384, densN, scl, true, Wtj, out, 1, Nn, n0, lin_s, attrs_s); break;
    case 2: skip2_body<5, 8>(attrs, msg, 2048, 16, 4, Wlin + 32768, densN, scl, true, Wtj, out, 4, Nn, n0, lin_s, attrs_s); break;
    case 3: skip2_body<7, 8>(attrs, msg, 2048, 16, 9, Wlin + 49152, densN, scl, true, Wtj, out, 9, Nn, n0, lin_s, attrs_s); break;
    case 4: skip2_body<1, 1>(attrs, mmr, 512, 4, 0, Wmlin, densN, sm, false, Wtj, out + (size_t)Nn * 2048, 0, Nn, n0, lin_s, attrs_s); break;
    case 5: skip2_body<3, 4>(attrs, mmr, 512, 4, 1, Wmlin + 16384, densN, sm, false, Wtj, out + (size_t)Nn * 2048, 1, Nn, n0, lin_s, attrs_s); break;
  }
}

// ---------------- fallback: round-4 fused gather + old 16-node skip ---------
__global__ __launch_bounds__(256) void k_gather_f(
    const float* __restrict__ x, const float* __restrict__ edge_attrs,
    const float* __restrict__ edge_feats, const float* __restrict__ mminv,
    const float* __restrict__ mmattrs, const int* __restrict__ sender,
    const float* __restrict__ W1, const float* __restrict__ W2,
    const float* __restrict__ W3, const float* __restrict__ W4,
    const float* __restrict__ Mc, const float* __restrict__ Wd,
    const float* __restrict__ Wlin, const float* __restrict__ Wmlin,
    const int* __restrict__ rowstart, const int* __restrict__ elist,
    float* __restrict__ linm, float* __restrict__ linmm, int Nn) {
  const int n = blockIdx.x;
  const int t = threadIdx.x;
  const int start = rowstart[n], end = rowstart[n + 1];

  __shared__ float ef[8][16];
  __shared__ float hA[8][64];
  __shared__ float hB[8][64];
  __shared__ float ubuf[8 * 512 + 8 * 256];
  __shared__ float xjs[8][128];
  __shared__ float shs[8][16];
  __shared__ float mmshs[8][4];
  __shared__ float denss[8];
  __shared__ int eS[8], sS[8];
  __shared__ float dsum_s;

  float (*w4s)[512] = (float (*)[512])ubuf;
  float (*wmms)[256] = (float (*)[256])(ubuf + 8 * 512);
  float (*msg_s)[17] = (float (*)[17])ubuf;
  float (*mm_s)[5] = (float (*)[5])(ubuf + 128 * 17);

  float accm[8] = {0, 0, 0, 0, 0, 0, 0, 0};
  float accmm0 = 0.f, accmm1 = 0.f;
  float accd = 0.f;

  const int u = t & 127;
  const int half = t >> 7;
  const int gwave = t >> 6;
  const int o6 = t & 63;

  for (int base = start; base < end; base += 8) {
    if (t < 8) {
      int g = t;
      if (base + g < end) {
        int e = elist[base + g];
        eS[g] = e;
        sS[g] = sender[e];
      } else {
        eS[g] = -1;
        sS[g] = 0;
        denss[g] = 0.f;
      }
    }
    __syncthreads();
    if (t < 128) {
      int g = t >> 4, j = t & 15;
      int e = eS[g];
      shs[g][j] = (e >= 0) ? edge_attrs[e * 16 + j] : 0.f;
      float v = 0.f;
      if (e >= 0) v = (j < 8) ? edge_feats[e * 8 + j] : mminv[sS[g] * 8 + (j - 8)];
      ef[g][j] = v;
    } else if (t < 160) {
      int g = (t - 128) >> 2, j = (t - 128) & 3;
      mmshs[g][j] = (eS[g] >= 0) ? mmattrs[sS[g] * 4 + j] : 0.f;
    }
    for (int i = t; i < 1024; i += 256) {
      int g = i >> 7, uu = i & 127;
      xjs[g][uu] = (eS[g] >= 0) ? x[(size_t)sS[g] * 128 + uu] : 0.f;
    }
    if (t < 8 && eS[t] >= 0) {
      int e = eS[t];
      float q = 0.f;
#pragma unroll
      for (int k = 0; k < 8; k++) q += edge_feats[e * 8 + k] * Wd[k];
      q *= 0.35355339059327373f;
      denss[t] = tanhf(q * q);
    }
    __syncthreads();

#pragma unroll
    for (int rep = 0; rep < 2; rep++) {
      int g = gwave + rep * 4;
      float s = 0.f;
#pragma unroll
      for (int k = 0; k < 16; k++) s += ef[g][k] * W1[k * 64 + o6];
      hA[g][o6] = silu_f(s * 0.25f);
    }
#pragma unroll
    for (int rep = 0; rep < 2; rep++) {
      int g = gwave + rep * 4;
      float s = 0.f;
#pragma unroll 8
      for (int k = 0; k < 64; k++) s += hA[g][k] * W2[k * 64 + o6];
      hB[g][o6] = silu_f(s * 0.125f);
    }
#pragma unroll
    for (int rep = 0; rep < 2; rep++) {
      int g = gwave + rep * 4;
      float s = 0.f;
#pragma unroll 8
      for (int k = 0; k < 64; k++) s += hB[g][k] * W3[k * 64 + o6];
      hA[g][o6] = silu_f(s * 0.125f);
    }
    __syncthreads();
    {
      float a[8] = {0, 0, 0, 0, 0, 0, 0, 0};
      float b[8] = {0, 0, 0, 0, 0, 0, 0, 0};
#pragma unroll 8
      for (int k = 0; k < 64; k++) {
        float w0 = W4[k * 512 + t];
        float w1 = W4[k * 512 + t + 256];
#pragma unroll
        for (int g = 0; g < 8; g++) {
          float h = hA[g][k];
          a[g] += h * w0;
          b[g] += h * w1;
        }
      }
      int p0 = (t & 3) * 128 + (t >> 2);
      int p1 = (t & 3) * 128 + 64 + (t >> 2);
#pragma unroll
      for (int g = 0; g < 8; g++) {
        w4s[g][p0] = a[g] * 0.125f;
        w4s[g][p1] = b[g] * 0.125f;
      }
    }
    {
      float c[8] = {0, 0, 0, 0, 0, 0, 0, 0};
#pragma unroll
      for (int k = 0; k < 16; k++) {
        float w = Mc[k * 256 + t];
#pragma unroll
        for (int g = 0; g < 8; g++) c[g] += ef[g][k] * w;
      }
      int p = (t & 1) * 128 + (t >> 1);
#pragma unroll
      for (int g = 0; g < 8; g++) wmms[g][p] = c[g];
    }
    __syncthreads();
#pragma unroll 2
    for (int g = 0; g < 8; g++) {
      float xj = xjs[g][u];
      float sh0 = shs[g][0];
      float w40 = w4s[g][u];
      float w41 = w4s[g][128 + u];
      float w42 = w4s[g][256 + u];
      float w43 = w4s[g][384 + u];
      float pre0 = w40 * xj * sh0;
      float wg0 = wmms[g][u] * pre0;
      float wg1 = wmms[g][128 + u] * pre0;
      float mm0 = wg0 * xj * mmshs[g][0];
      float m1 = wg1 * xj;
      float bx = mm0 * xj;
      float b0 = w40 * bx, b1 = w41 * bx, b2 = w42 * bx, b3 = w43 * bx;
      if (half == 0) {
        accmm0 += mm0;
        accmm1 += m1 * mmshs[g][1];
        accm[0] += b0 * sh0;
        accm[1] += b1 * shs[g][1];
        accm[2] += b1 * shs[g][2];
        accm[3] += b1 * shs[g][3];
        accm[4] += b2 * shs[g][4];
        accm[5] += b2 * shs[g][5];
        accm[6] += b2 * shs[g][6];
        accm[7] += b2 * shs[g][7];
      } else {
        accmm0 += m1 * mmshs[g][2];
        accmm1 += m1 * mmshs[g][3];
        accm[0] += b2 * shs[g][8];
        accm[1] += b3 * shs[g][9];
        accm[2] += b3 * shs[g][10];
        accm[3] += b3 * shs[g][11];
        accm[4] += b3 * shs[g][12];
        accm[5] += b3 * shs[g][13];
        accm[6] += b3 * shs[g][14];
        accm[7] += b3 * shs[g][15];
      }
    }
    if (t == 0) {
#pragma unroll
      for (int g = 0; g < 8; g++) accd += denss[g];
    }
  }

  __syncthreads();
#pragma unroll
  for (int j = 0; j < 8; j++) msg_s[u][half * 8 + j] = accm[j];
  mm_s[u][half * 2 + 0] = accmm0;
  mm_s[u][half * 2 + 1] = accmm1;
  if (t == 0) dsum_s = accd;
  __syncthreads();
  const float dinv = 1.0f / (dsum_s + 1.0f);

  float outl[8] = {0, 0, 0, 0, 0, 0, 0, 0};
  if (half == 0) {
    for (int uu = 0; uu < 128; uu++) {
      float wl0 = Wlin[uu * 128 + u];
      float wl1 = Wlin[16384 + uu * 128 + u];
      float wl2 = Wlin[32768 + uu * 128 + u];
      outl[0] += msg_s[uu][0] * wl0;
      outl[1] += msg_s[uu][1] * wl1;
      outl[2] += msg_s[uu][2] * wl1;
      outl[3] += msg_s[uu][3] * wl1;
      outl[4] += msg_s[uu][4] * wl2;
      outl[5] += msg_s[uu][5] * wl2;
      outl[6] += msg_s[uu][6] * wl2;
      outl[7] += msg_s[uu][7] * wl2;
    }
  } else {
    for (int uu = 0; uu < 128; uu++) {
      float wl2 = Wlin[32768 + uu * 128 + u];
      float wl3 = Wlin[49152 + uu * 128 + u];
      outl[0] += msg_s[uu][8] * wl2;
      outl[1] += msg_s[uu][9] * wl3;
      outl[2] += msg_s[uu][10] * wl3;
      outl[3] += msg_s[uu][11] * wl3;
      outl[4] += msg_s[uu][12] * wl3;
      outl[5] += msg_s[uu][13] * wl3;
      outl[6] += msg_s[uu][14] * wl3;
      outl[7] += msg_s[uu][15] * wl3;
    }
  }
  const float sclv = 0.08838834764831845f * dinv;
  float4 v0 = make_float4(outl[0] * sclv, outl[1] * sclv, outl[2] * sclv, outl[3] * sclv);
  float4 v1 = make_float4(outl[4] * sclv, outl[5] * sclv, outl[6] * sclv, outl[7] * sclv);
  float4* lp = (float4*)(linm + (size_t)n * 2048 + u * 16 + half * 8);
  lp[0] = v0;
  lp[1] = v1;

  float om0 = 0.f, om1 = 0.f;
  if (half == 0) {
    for (int uu = 0; uu < 128; uu++) {
      om0 += mm_s[uu][0] * Wmlin[uu * 128 + u];
      om1 += mm_s[uu][1] * Wmlin[16384 + uu * 128 + u];
    }
  } else {
    for (int uu = 0; uu < 128; uu++) {
      float wm1 = Wmlin[16384 + uu * 128 + u];
      om0 += mm_s[uu][2] * wm1;
      om1 += mm_s[uu][3] * wm1;
    }
  }
  const float sm = 0.08838834764831845f / 20.0f;
  *(float2*)(linmm + (size_t)n * 512 + u * 4 + half * 2) = make_float2(om0 * sm, om1 * sm);
}

// old skip (fallback path), 16-node tiles, fp16 Wt
template <int D, int SP>
__device__ __forceinline__ void skip_body2(
    const float* __restrict__ attrs, const float* __restrict__ in, int in_rs,
    int in_us, int in_cb, const __half* __restrict__ Wt, float* __restrict__ outp,
    int out_cb, int Nn, int n0, float* lin_s, float (*attrs_s)[10]) {
  const int t = threadIdx.x;
  for (int i = t; i < 160; i += 256) {
    int nn = i / 10, z = i - nn * 10;
    int n = n0 + nn;
    attrs_s[nn][z] = (n < Nn) ? attrs[n * 10 + z] : 0.f;
  }
  for (int i = t; i < 16 * 128 * D; i += 256) {
    int nn = i / (128 * D);
    int r = i - nn * 128 * D;
    int uu = r / D;
    int m = r - uu * D;
    int n = n0 + nn;
    lin_s[(nn * 128 + uu) * SP + m] =
        (n < Nn) ? in[(size_t)n * in_rs + uu * in_us + in_cb + m] : 0.f;
  }
  __syncthreads();

  const int v = t & 127, hf = t >> 7;
  float ar[8][10];
#pragma unroll
  for (int q = 0; q < 8; q++)
#pragma unroll
    for (int z = 0; z < 10; z++) ar[q][z] = attrs_s[hf * 8 + q][z];

  float acc[8][D];
#pragma unroll
  for (int q = 0; q < 8; q++)
#pragma unroll
    for (int m = 0; m < D; m++) acc[q][m] = 0.f;

  const __half* wp0 = Wt + (size_t)v * 12;
  for (int u = 0; u < 128; u++) {
    const __half* wp = wp0 + (size_t)u * 1536;
    const float2* fp = (const float2*)wp;
    float2 q0 = fp[0];
    float2 q1 = fp[1];
    float2 q2 = fp[2];
    F2H2 c0, c1, c2, c3, c4;
    c0.f = q0.x; c1.f = q0.y; c2.f = q1.x; c3.f = q1.y; c4.f = q2.x;
    float wr[10];
    wr[0] = __low2float(c0.h); wr[1] = __high2float(c0.h);
    wr[2] = __low2float(c1.h); wr[3] = __high2float(c1.h);
    wr[4] = __low2float(c2.h); wr[5] = __high2float(c2.h);
    wr[6] = __low2float(c3.h); wr[7] = __high2float(c3.h);
    wr[8] = __low2float(c4.h); wr[9] = __high2float(c4.h);
#pragma unroll
    for (int q = 0; q < 8; q++) {
      float wn = 0.f;
#pragma unroll
      for (int z = 0; z < 10; z++) wn += ar[q][z] * wr[z];
      const float* ls = &lin_s[((hf * 8 + q) * 128 + u) * SP];
#pragma unroll
      for (int m = 0; m < D; m++) acc[q][m] += ls[m] * wn;
    }
  }
#pragma unroll
  for (int q = 0; q < 8; q++) {
    int n = n0 + hf * 8 + q;
    if (n < Nn) {
      float* op = outp + (size_t)n * 2048 + v * 16 + out_cb;
#pragma unroll
      for (int m = 0; m < D; m++) op[m] = acc[q][m] * 0.027950849718747371f;
    }
  }
}

__global__ __launch_bounds__(256) void k_skip(
    const float* __restrict__ attrs, const float* __restrict__ linm,
    const float* __restrict__ linmm, const __half* __restrict__ Wt,
    float* __restrict__ out, int Nn) {
  __shared__ float lin_s[16 * 128 * 8];
  __shared__ float attrs_s[16][10];
  const int n0 = blockIdx.x * 16;
  const int job = blockIdx.y;
  const __half* Wtj = Wt + (size_t)job * 128 * 128 * 12;
  switch (job) {
    case 0: skip_body2<1, 1>(attrs, linm, 2048, 16, 0, Wtj, out, 0, Nn, n0, lin_s, attrs_s); break;
    case 1: skip_body2<3, 4>(attrs, linm, 2048, 16, 1, Wtj, out, 1, Nn, n0, lin_s, attrs_s); break;
    case 2: skip_body2<5, 8>(attrs, linm, 2048, 16, 4, Wtj, out, 4, Nn, n0, lin_s, attrs_s); break;
    case 3: skip_body2<7, 8>(attrs, linm, 2048, 16, 9, Wtj, out, 9, Nn, n0, lin_s, attrs_s); break;
    case 4: skip_body2<1, 1>(attrs, linmm, 512, 4, 0, Wtj, out + (size_t)Nn * 2048, 0, Nn, n0, lin_s, attrs_s); break;
    case 5: skip_body2<3, 4>(attrs, linmm, 512, 4, 1, Wtj, out + (size_t)Nn * 2048, 1, Nn, n0, lin_s, attrs_s); break;
  }
}

extern "C" void kernel_launch(void* const* d_in, const int* in_sizes, int n_in,
                              void* d_out, int out_size, void* d_ws, size_t ws_size,
                              hipStream_t stream) {
  const float* node_attrs = (const float*)d_in[0];
  const float* node_feats = (const float*)d_in[1];
  const float* edge_attrs = (const float*)d_in[2];
  const float* edge_feats = (const float*)d_in[3];
  const float* mminv = (const float*)d_in[4];
  const float* mmattrs = (const float*)d_in[5];
  const int* edge_index = (const int*)d_in[6];
  const float* W_up = (const float*)d_in[7];
  const float* W1 = (const float*)d_in[8];
  const float* W2 = (const float*)d_in[9];
  const float* W3 = (const float*)d_in[10];
  const float* W4 = (const float*)d_in[11];
  const float* M1 = (const float*)d_in[12];
  const float* M2 = (const float*)d_in[13];
  const float* M3 = (const float*)d_in[14];
  const float* M4 = (const float*)d_in[15];
  const float* Wd = (const float*)d_in[16];
  const float* Wlin = (const float*)d_in[17];
  const float* Wmlin = (const float*)d_in[18];
  const float* Wskip = (const float*)d_in[19];
  const float* Wmskip = (const float*)d_in[20];

  const int N = in_sizes[1] / 128;
  const int E = in_sizes[2] / 16;
  const int* sender = edge_index;
  const int* recv = edge_index + E;

  float* ws = (float*)d_ws;
  float* x = ws;     ws += (size_t)N * 128;
  float* Mc = ws;    ws += 16 * 256;
  __half* Wt = (__half*)ws;  ws += (size_t)6 * 128 * 128 * 12 / 2;  // fp16
  float* msg = ws;   ws += (size_t)N * 2048;   // fallback: linm
  float* mmr = ws;   ws += (size_t)N * 512;    // fallback: linmm
  float* densN = ws; ws += N;
  float* dens = ws;  ws += E;
  int* ibuf = (int*)ws;
  int* rowstart = ibuf;            // N+1
  int* deg = ibuf + (N + 1);       // N
  int* cursor = deg + N;           // N
  int* elist = cursor + N;         // E
  char* tail = (char*)(((uintptr_t)(elist + E) + 63) & ~(uintptr_t)63);
  size_t tailOff = (size_t)(tail - (char*)d_ws);
  size_t needA2 = tailOff + (size_t)E * 512 * 2 + (size_t)E * 256 * 2 + 256;  // ~211 MB
  size_t needA = tailOff + (size_t)E * 512 * 2 + 256;                         // ~160 MB (proven fits)
  __half* w4e = (__half*)tail;
  __half* wmme_h = (__half*)(tail + (size_t)E * 512 * 2);
  const int mode = (ws_size >= needA2) ? 0 : (ws_size >= needA ? 1 : 2);

  k_zero_int<<<(N + 255) / 256, 256, 0, stream>>>(deg, N);
  k_prep<<<1, 256, 0, stream>>>(M1, M2, M3, M4, Mc);
  k_wt<<<768, 128, 0, stream>>>(Wskip, Wmskip, Wt);
  k_up<<<N, 128, 0, stream>>>(node_feats, W_up, x, N);
  k_count<<<(E + 255) / 256, 256, 0, stream>>>(recv, deg, E);
  k_scan<<<1, 1024, 0, stream>>>(deg, rowstart, cursor, N);
  k_fill<<<(E + 255) / 256, 256, 0, stream>>>(recv, cursor, elist, E);

  if (mode == 0) {
    k_edge_w4<<<(E + 7) / 8, 256, 0, stream>>>(edge_feats, mminv, sender, W1,
                                               W2, W3, W4, Mc, Wd, w4e, wmme_h,
                                               dens, E);
    k_gather_c2<<<N, 256, 0, stream>>>(x, edge_attrs, mmattrs, sender, w4e,
                                       wmme_h, dens, rowstart, elist, msg, mmr,
                                       densN, N);
    k_zero2<<<(N * 128 + 255) / 256, 256, 0, stream>>>((float*)d_out + (size_t)N * 2048, N);
    dim3 gs2((N + 7) / 8, 6);
    k_skip2<<<gs2, 256, 0, stream>>>(node_attrs, msg, mmr, densN, Wlin, Wmlin,
                                     Wt, (float*)d_out, N);
  } else if (mode == 1) {
    k_edge_w4<<<(E + 7) / 8, 256, 0, stream>>>(edge_feats, mminv, sender, W1,
                                               W2, W3, W4, Mc, Wd, w4e,
                                               (__half*)nullptr, dens, E);
    k_gather_c<<<N, 256, 0, stream>>>(x, edge_attrs, edge_feats, mminv,
                                      mmattrs, sender, Mc, w4e, dens, rowstart,
                                      elist, msg, mmr, densN, N);
    k_zero2<<<(N * 128 + 255) / 256, 256, 0, stream>>>((float*)d_out + (size_t)N * 2048, N);
    dim3 gs2((N + 7) / 8, 6);
    k_skip2<<<gs2, 256, 0, stream>>>(node_attrs, msg, mmr, densN, Wlin, Wmlin,
                                     Wt, (float*)d_out, N);
  } else {
    k_gather_f<<<N, 256, 0, stream>>>(x, edge_attrs, edge_feats, mminv,
                                      mmattrs, sender, W1, W2, W3, W4, Mc, Wd,
                                      Wlin, Wmlin, rowstart, elist, msg, mmr, N);
    k_zero2<<<(N * 128 + 255) / 256, 256, 0, stream>>>((float*)d_out + (size_t)N * 2048, N);
    dim3 gs((N + 15) / 16, 6);
    k_skip<<<gs, 256, 0, stream>>>(node_attrs, msg, mmr, Wt, (float*)d_out, N);
  }
}

// Round 15
// 808.692 us; speedup vs baseline: 1.0729x; 1.0729x over previous
//
#include <hip/hip_runtime.h>
#include <hip/hip_fp16.h>
#include <stdint.h>

// MUL=128, Z=10, L_DIMS=(1,3,5,7) offs (0,1,4,9), MM_DIMS=(1,3)

__device__ __forceinline__ float silu_f(float x) {
  return x / (1.0f + __expf(-x));
}

union F2H2 { float f; __half2 h; };

typedef _Float16 hv2 __attribute__((ext_vector_type(2)));
union FHV { float f; hv2 h; };

#if defined(__has_builtin)
#if __has_builtin(__builtin_amdgcn_fdot2)
#define HAS_FDOT2 1
#endif
#endif

// wn = sum_{z=0..9} ar[z] * wr[z] with both sides fp16 pairs
__device__ __forceinline__ float wn_dot(const hv2* ar, const hv2* wr) {
#ifdef HAS_FDOT2
  float s = 0.f;
#pragma unroll
  for (int z = 0; z < 5; z++) s = __builtin_amdgcn_fdot2(ar[z], wr[z], s, false);
  return s;
#else
  float s = 0.f;
#pragma unroll
  for (int z = 0; z < 5; z++)
    s += (float)ar[z][0] * (float)wr[z][0] + (float)ar[z][1] * (float)wr[z][1];
  return s;
#endif
}

__global__ void k_zero_int(int* p, int n) {
  int i = blockIdx.x * blockDim.x + threadIdx.x;
  if (i < n) p[i] = 0;
}

// Mc = M1@M2@M3@M4 / 2048  (linear MLP collapse), Mc is [16,256]
__global__ __launch_bounds__(256) void k_prep(
    const float* __restrict__ M1, const float* __restrict__ M2,
    const float* __restrict__ M3, const float* __restrict__ M4,
    float* __restrict__ Mc) {
  __shared__ float T1[16 * 64];
  __shared__ float T2[16 * 64];
  int t = threadIdx.x;
  for (int i = t; i < 16 * 64; i += 256) {
    int r = i >> 6, c = i & 63;
    float s = 0.f;
    for (int k = 0; k < 64; k++) s += M1[r * 64 + k] * M2[k * 64 + c];
    T1[i] = s;
  }
  __syncthreads();
  for (int i = t; i < 16 * 64; i += 256) {
    int r = i >> 6, c = i & 63;
    float s = 0.f;
    for (int k = 0; k < 64; k++) s += T1[r * 64 + k] * M3[k * 64 + c];
    T2[i] = s;
  }
  __syncthreads();
  for (int i = t; i < 16 * 256; i += 256) {
    int r = i >> 8, c = i & 255;
    float s = 0.f;
    for (int k = 0; k < 64; k++) s += T2[r * 64 + k] * M4[k * 256 + c];
    Mc[i] = s * (1.0f / 2048.0f);
  }
}

// W4h[k*256+t] = (half(W4[k][t]), half(W4[k][t+256])) — mode-B gather stream.
__global__ __launch_bounds__(256) void k_w4h(const float* __restrict__ W4,
                                             __half2* __restrict__ W4h) {
  int k = blockIdx.x;   // 0..63
  int t = threadIdx.x;  // 0..255
  W4h[k * 256 + t] =
      __halves2half2(__float2half(W4[k * 512 + t]), __float2half(W4[k * 512 + t + 256]));
}

// x = node_feats @ W_up / sqrt(128)   one block per node, 128 threads
__global__ __launch_bounds__(128) void k_up(const float* __restrict__ nf,
                                            const float* __restrict__ W,
                                            float* __restrict__ x, int Nn) {
  int n = blockIdx.x;
  int v = threadIdx.x;
  __shared__ float row[128];
  row[v] = nf[n * 128 + v];
  __syncthreads();
  float s = 0.f;
#pragma unroll 8
  for (int k = 0; k < 128; k++) s += row[k] * W[k * 128 + v];
  x[n * 128 + v] = s * 0.08838834764831845f;
}

__global__ void k_count(const int* __restrict__ recv, int* __restrict__ deg, int E) {
  int e = blockIdx.x * blockDim.x + threadIdx.x;
  if (e < E) atomicAdd(&deg[recv[e]], 1);
}

// exclusive scan of deg -> rowstart[0..N], cursor copy. single block 1024 threads.
__global__ __launch_bounds__(1024) void k_scan(const int* __restrict__ deg,
                                               int* __restrict__ rowstart,
                                               int* __restrict__ cursor, int Nn) {
  __shared__ int part[1024];
  int t = threadIdx.x;
  int chunk = (Nn + 1023) / 1024;
  int lo = t * chunk;
  int hi = lo + chunk; if (hi > Nn) hi = Nn; if (lo > Nn) lo = Nn;
  int s = 0;
  for (int i = lo; i < hi; i++) s += deg[i];
  part[t] = s;
  __syncthreads();
  for (int o = 1; o < 1024; o <<= 1) {
    int v = (t >= o) ? part[t - o] : 0;
    __syncthreads();
    part[t] += v;
    __syncthreads();
  }
  int base = (t == 0) ? 0 : part[t - 1];
  for (int i = lo; i < hi; i++) {
    rowstart[i] = base;
    cursor[i] = base;
    base += deg[i];
  }
  if (t == 1023) rowstart[Nn] = part[1023];
}

__global__ void k_fill(const int* __restrict__ recv, int* __restrict__ cursor,
                       int* __restrict__ elist, int E) {
  int e = blockIdx.x * blockDim.x + threadIdx.x;
  if (e < E) {
    int p = atomicAdd(&cursor[recv[e]], 1);
    elist[p] = e;
  }
}

// ---------------- mode A: edge kernel with full W4 GEMM ---------------------
__global__ __launch_bounds__(256) void k_edge_w4(
    const float* __restrict__ edge_feats, const float* __restrict__ mminv,
    const int* __restrict__ sender,
    const float* __restrict__ W1, const float* __restrict__ W2,
    const float* __restrict__ W3, const float* __restrict__ W4,
    const float* __restrict__ Wd, __half* __restrict__ w4e,
    float* __restrict__ dens, int E) {
  const int base = blockIdx.x * 8;
  const int t = threadIdx.x;
  __shared__ float ef[8][16];
  __shared__ float hA[8][64];
  __shared__ float hB[8][64];
  __shared__ float w4s[8][512];
  const int gwave = t >> 6;
  const int o6 = t & 63;

  if (t < 128) {
    int g = t >> 4, j = t & 15;
    int e = base + g;
    float v = 0.f;
    if (e < E) v = (j < 8) ? edge_feats[e * 8 + j] : mminv[sender[e] * 8 + (j - 8)];
    ef[g][j] = v;
  } else if (t < 136) {
    int g = t - 128;
    int e = base + g;
    if (e < E) {
      float q = 0.f;
#pragma unroll
      for (int k = 0; k < 8; k++) q += edge_feats[e * 8 + k] * Wd[k];
      q *= 0.35355339059327373f;
      dens[e] = tanhf(q * q);
    }
  }
  __syncthreads();

#pragma unroll
  for (int rep = 0; rep < 2; rep++) {
    int g = gwave + rep * 4;
    float s = 0.f;
#pragma unroll
    for (int k = 0; k < 16; k++) s += ef[g][k] * W1[k * 64 + o6];
    hA[g][o6] = silu_f(s * 0.25f);
  }
#pragma unroll
  for (int rep = 0; rep < 2; rep++) {
    int g = gwave + rep * 4;
    float s = 0.f;
#pragma unroll 8
    for (int k = 0; k < 64; k++) s += hA[g][k] * W2[k * 64 + o6];
    hB[g][o6] = silu_f(s * 0.125f);
  }
#pragma unroll
  for (int rep = 0; rep < 2; rep++) {
    int g = gwave + rep * 4;
    float s = 0.f;
#pragma unroll 8
    for (int k = 0; k < 64; k++) s += hB[g][k] * W3[k * 64 + o6];
    hA[g][o6] = silu_f(s * 0.125f);
  }
  __syncthreads();  // hA visible cross-wave

  {
    float a[8] = {0, 0, 0, 0, 0, 0, 0, 0};
    float b[8] = {0, 0, 0, 0, 0, 0, 0, 0};
#pragma unroll 8
    for (int k = 0; k < 64; k++) {
      float w0 = W4[k * 512 + t];
      float w1 = W4[k * 512 + t + 256];
#pragma unroll
      for (int g = 0; g < 8; g++) {
        float h = hA[g][k];
        a[g] += h * w0;
        b[g] += h * w1;
      }
    }
    int p0 = (t & 3) * 128 + (t >> 2);
    int p1 = (t & 3) * 128 + 64 + (t >> 2);
#pragma unroll
    for (int g = 0; g < 8; g++) {
      w4s[g][p0] = a[g] * 0.125f;
      w4s[g][p1] = b[g] * 0.125f;
    }
  }
  __syncthreads();  // w4s visible

  __half2* dst = (__half2*)w4e;
#pragma unroll
  for (int g = 0; g < 8; g++) {
    int e = base + g;
    if (e < E) {
      dst[(size_t)e * 256 + t] =
          __halves2half2(__float2half(w4s[g][2 * t]), __float2half(w4s[g][2 * t + 1]));
    }
  }
}

// ---------------- mode A: gather consuming precomputed w4e ------------------
__global__ __launch_bounds__(256) void k_gather_c(
    const float* __restrict__ x, const float* __restrict__ edge_attrs,
    const float* __restrict__ edge_feats, const float* __restrict__ mminv,
    const float* __restrict__ mmattrs, const int* __restrict__ sender,
    const float* __restrict__ Mc, const __half* __restrict__ w4e,
    const float* __restrict__ dens,
    const int* __restrict__ rowstart, const int* __restrict__ elist,
    float* __restrict__ msg, float* __restrict__ mmr, float* __restrict__ densN,
    int Nn) {
  const int n = blockIdx.x;
  const int t = threadIdx.x;
  const int start = rowstart[n], end = rowstart[n + 1];

  __shared__ float ef[8][16];
  __shared__ float wmms[8][256];
  __shared__ float xjs[8][128];
  __shared__ float shs[8][16];
  __shared__ float mmshs[8][4];
  __shared__ float denss[8];
  __shared__ int eS[8], sS[8];

  float accm[8] = {0, 0, 0, 0, 0, 0, 0, 0};
  float accmm0 = 0.f, accmm1 = 0.f;
  float accd = 0.f;

  const int u = t & 127;
  const int half = t >> 7;  // wave-uniform

  for (int base = start; base < end; base += 8) {
    if (t < 8) {
      int g = t;
      if (base + g < end) {
        int e = elist[base + g];
        eS[g] = e;
        sS[g] = sender[e];
        denss[g] = dens[e];
      } else {
        eS[g] = -1;
        sS[g] = 0;
        denss[g] = 0.f;
      }
    }
    __syncthreads();  // B: eS/sS/denss visible
    int erA[8];
#pragma unroll
    for (int g = 0; g < 8; g++) {
      int ev = eS[g];
      erA[g] = ev < 0 ? 0 : ev;  // captured before C; writers pass C first
    }
    if (t < 128) {
      int g = t >> 4, j = t & 15;
      int e = eS[g];
      shs[g][j] = (e >= 0) ? edge_attrs[e * 16 + j] : 0.f;
      float v = 0.f;
      if (e >= 0) v = (j < 8) ? edge_feats[e * 8 + j] : mminv[sS[g] * 8 + (j - 8)];
      ef[g][j] = v;
    } else if (t < 160) {
      int g = (t - 128) >> 2, j = (t - 128) & 3;
      mmshs[g][j] = (eS[g] >= 0) ? mmattrs[sS[g] * 4 + j] : 0.f;
    }
    for (int i = t; i < 1024; i += 256) {
      int g = i >> 7, uu = i & 127;
      xjs[g][uu] = (eS[g] >= 0) ? x[(size_t)sS[g] * 128 + uu] : 0.f;
    }
    __syncthreads();  // C: staged data visible

    {
      float c[8] = {0, 0, 0, 0, 0, 0, 0, 0};
#pragma unroll
      for (int k = 0; k < 16; k++) {
        float w = Mc[k * 256 + t];
#pragma unroll
        for (int g = 0; g < 8; g++) c[g] += ef[g][k] * w;
      }
      int p = (t & 1) * 128 + (t >> 1);
#pragma unroll
      for (int g = 0; g < 8; g++) wmms[g][p] = c[g];
    }
    __syncthreads();  // E: wmms visible

#pragma unroll 2
    for (int g = 0; g < 8; g++) {
      const __half* w4g = w4e + (size_t)erA[g] * 512;
      float w40 = __half2float(w4g[u]);
      float w41 = __half2float(w4g[128 + u]);
      float w42 = __half2float(w4g[256 + u]);
      float w43 = __half2float(w4g[384 + u]);
      float wm0 = wmms[g][u];
      float wm1 = wmms[g][128 + u];
      float xj = xjs[g][u];
      float sh0 = shs[g][0];
      float pre0 = w40 * xj * sh0;
      float wg0 = wm0 * pre0;
      float wg1 = wm1 * pre0;
      float mm0 = wg0 * xj * mmshs[g][0];
      float m1 = wg1 * xj;
      float bx = mm0 * xj;
      float b0 = w40 * bx, b1 = w41 * bx, b2 = w42 * bx, b3 = w43 * bx;
      if (half == 0) {
        accmm0 += mm0;
        accmm1 += m1 * mmshs[g][1];
        accm[0] += b0 * sh0;
        accm[1] += b1 * shs[g][1];
        accm[2] += b1 * shs[g][2];
        accm[3] += b1 * shs[g][3];
        accm[4] += b2 * shs[g][4];
        accm[5] += b2 * shs[g][5];
        accm[6] += b2 * shs[g][6];
        accm[7] += b2 * shs[g][7];
      } else {
        accmm0 += m1 * mmshs[g][2];
        accmm1 += m1 * mmshs[g][3];
        accm[0] += b2 * shs[g][8];
        accm[1] += b3 * shs[g][9];
        accm[2] += b3 * shs[g][10];
        accm[3] += b3 * shs[g][11];
        accm[4] += b3 * shs[g][12];
        accm[5] += b3 * shs[g][13];
        accm[6] += b3 * shs[g][14];
        accm[7] += b3 * shs[g][15];
      }
    }
    if (t == 0) {
#pragma unroll
      for (int g = 0; g < 8; g++) accd += denss[g];  // same wave as writers
    }
  }

  float4* mp = (float4*)(msg + (size_t)n * 2048 + u * 16 + half * 8);
  mp[0] = make_float4(accm[0], accm[1], accm[2], accm[3]);
  mp[1] = make_float4(accm[4], accm[5], accm[6], accm[7]);
  *(float2*)(mmr + (size_t)n * 512 + u * 4 + half * 2) = make_float2(accmm0, accmm1);
  if (t == 0) densN[n] = accd;
}

// ---------------- mode B: edge-parallel radial MLP producer -----------------
__global__ __launch_bounds__(256) void k_edge_hA(
    const float* __restrict__ edge_feats, const float* __restrict__ mminv,
    const int* __restrict__ sender,
    const float* __restrict__ W1, const float* __restrict__ W2,
    const float* __restrict__ W3, const float* __restrict__ Wd,
    float* __restrict__ hAe, float* __restrict__ dens, int E) {
  const int base = blockIdx.x * 8;
  const int t = threadIdx.x;
  __shared__ float ef[8][16];
  __shared__ float hA[8][64];
  __shared__ float hB[8][64];
  const int gwave = t >> 6;
  const int o6 = t & 63;

  if (t < 128) {
    int g = t >> 4, j = t & 15;
    int e = base + g;
    float v = 0.f;
    if (e < E) v = (j < 8) ? edge_feats[e * 8 + j] : mminv[sender[e] * 8 + (j - 8)];
    ef[g][j] = v;
  } else if (t < 136) {
    int g = t - 128;
    int e = base + g;
    if (e < E) {
      float q = 0.f;
#pragma unroll
      for (int k = 0; k < 8; k++) q += edge_feats[e * 8 + k] * Wd[k];
      q *= 0.35355339059327373f;
      dens[e] = tanhf(q * q);
    }
  }
  __syncthreads();

#pragma unroll
  for (int rep = 0; rep < 2; rep++) {
    int g = gwave + rep * 4;
    float s = 0.f;
#pragma unroll
    for (int k = 0; k < 16; k++) s += ef[g][k] * W1[k * 64 + o6];
    hA[g][o6] = silu_f(s * 0.25f);
  }
#pragma unroll
  for (int rep = 0; rep < 2; rep++) {
    int g = gwave + rep * 4;
    float s = 0.f;
#pragma unroll 8
    for (int k = 0; k < 64; k++) s += hA[g][k] * W2[k * 64 + o6];
    hB[g][o6] = silu_f(s * 0.125f);
  }
#pragma unroll
  for (int rep = 0; rep < 2; rep++) {
    int g = gwave + rep * 4;
    float s = 0.f;
#pragma unroll 8
    for (int k = 0; k < 64; k++) s += hB[g][k] * W3[k * 64 + o6];
    int e = base + g;
    if (e < E) hAe[(size_t)e * 64 + o6] = silu_f(s * 0.125f);
  }
}

// ---------------- mode B: per-node gather (fp16 W4 stream) ------------------
__global__ __launch_bounds__(256) void k_gather_raw(
    const float* __restrict__ x, const float* __restrict__ edge_attrs,
    const float* __restrict__ edge_feats, const float* __restrict__ mminv,
    const float* __restrict__ mmattrs, const int* __restrict__ sender,
    const __half2* __restrict__ W4h, const float* __restrict__ Mc,
    const float* __restrict__ dens, const float* __restrict__ hAe,
    const int* __restrict__ rowstart, const int* __restrict__ elist,
    float* __restrict__ msg, float* __restrict__ mmr, float* __restrict__ densN,
    int Nn) {
  const int n = blockIdx.x;
  const int t = threadIdx.x;
  const int start = rowstart[n], end = rowstart[n + 1];

  __shared__ float ef[8][16];
  __shared__ float hA[8][64];
  __shared__ float ubuf[8 * 512 + 8 * 256];  // w4s[8][512] + wmms[8][256]
  __shared__ float xjs[8][128];
  __shared__ float shs[8][16];
  __shared__ float mmshs[8][4];
  __shared__ float denss[8];
  __shared__ int eS[8], sS[8];

  float (*w4s)[512] = (float (*)[512])ubuf;
  float (*wmms)[256] = (float (*)[256])(ubuf + 8 * 512);

  float accm[8] = {0, 0, 0, 0, 0, 0, 0, 0};
  float accmm0 = 0.f, accmm1 = 0.f;
  float accd = 0.f;

  const int u = t & 127;
  const int half = t >> 7;  // wave-uniform

  for (int base = start; base < end; base += 8) {
    if (t < 8) {
      int g = t;
      if (base + g < end) {
        int e = elist[base + g];
        eS[g] = e;
        sS[g] = sender[e];
        denss[g] = dens[e];
      } else {
        eS[g] = -1;
        sS[g] = 0;
        denss[g] = 0.f;
      }
    }
    __syncthreads();  // B
    if (t < 128) {
      int g = t >> 4, j = t & 15;
      int e = eS[g];
      shs[g][j] = (e >= 0) ? edge_attrs[e * 16 + j] : 0.f;
      float v = 0.f;
      if (e >= 0) v = (j < 8) ? edge_feats[e * 8 + j] : mminv[sS[g] * 8 + (j - 8)];
      ef[g][j] = v;
    } else if (t < 160) {
      int g = (t - 128) >> 2, j = (t - 128) & 3;
      mmshs[g][j] = (eS[g] >= 0) ? mmattrs[sS[g] * 4 + j] : 0.f;
    }
    for (int i = t; i < 1024; i += 256) {
      int g = i >> 7, uu = i & 127;
      xjs[g][uu] = (eS[g] >= 0) ? x[(size_t)sS[g] * 128 + uu] : 0.f;
    }
    for (int i = t; i < 512; i += 256) {
      int g = i >> 6, k = i & 63;
      hA[g][k] = (eS[g] >= 0) ? hAe[(size_t)eS[g] * 64 + k] : 0.f;
    }
    __syncthreads();  // C

    {
      float a[8] = {0, 0, 0, 0, 0, 0, 0, 0};
      float b[8] = {0, 0, 0, 0, 0, 0, 0, 0};
#pragma unroll 8
      for (int k = 0; k < 64; k++) {
        __half2 w2 = W4h[k * 256 + t];
        float w0 = __low2float(w2);
        float w1 = __high2float(w2);
#pragma unroll
        for (int g = 0; g < 8; g++) {
          float h = hA[g][k];
          a[g] += h * w0;
          b[g] += h * w1;
        }
      }
      int p0 = (t & 3) * 128 + (t >> 2);
      int p1 = (t & 3) * 128 + 64 + (t >> 2);
#pragma unroll
      for (int g = 0; g < 8; g++) {
        w4s[g][p0] = a[g] * 0.125f;
        w4s[g][p1] = b[g] * 0.125f;
      }
    }
    {
      float c[8] = {0, 0, 0, 0, 0, 0, 0, 0};
#pragma unroll
      for (int k = 0; k < 16; k++) {
        float w = Mc[k * 256 + t];
#pragma unroll
        for (int g = 0; g < 8; g++) c[g] += ef[g][k] * w;
      }
      int p = (t & 1) * 128 + (t >> 1);
#pragma unroll
      for (int g = 0; g < 8; g++) wmms[g][p] = c[g];
    }
    __syncthreads();  // E

#pragma unroll 2
    for (int g = 0; g < 8; g++) {
      float w40 = w4s[g][u];
      float w41 = w4s[g][128 + u];
      float w42 = w4s[g][256 + u];
      float w43 = w4s[g][384 + u];
      float wm0 = wmms[g][u];
      float wm1 = wmms[g][128 + u];
      float xj = xjs[g][u];
      float sh0 = shs[g][0];
      float pre0 = w40 * xj * sh0;
      float wg0 = wm0 * pre0;
      float wg1 = wm1 * pre0;
      float mm0 = wg0 * xj * mmshs[g][0];
      float m1 = wg1 * xj;
      float bx = mm0 * xj;
      float b0 = w40 * bx, b1 = w41 * bx, b2 = w42 * bx, b3 = w43 * bx;
      if (half == 0) {
        accmm0 += mm0;
        accmm1 += m1 * mmshs[g][1];
        accm[0] += b0 * sh0;
        accm[1] += b1 * shs[g][1];
        accm[2] += b1 * shs[g][2];
        accm[3] += b1 * shs[g][3];
        accm[4] += b2 * shs[g][4];
        accm[5] += b2 * shs[g][5];
        accm[6] += b2 * shs[g][6];
        accm[7] += b2 * shs[g][7];
      } else {
        accmm0 += m1 * mmshs[g][2];
        accmm1 += m1 * mmshs[g][3];
        accm[0] += b2 * shs[g][8];
        accm[1] += b3 * shs[g][9];
        accm[2] += b3 * shs[g][10];
        accm[3] += b3 * shs[g][11];
        accm[4] += b3 * shs[g][12];
        accm[5] += b3 * shs[g][13];
        accm[6] += b3 * shs[g][14];
        accm[7] += b3 * shs[g][15];
      }
    }
    if (t == 0) {
#pragma unroll
      for (int g = 0; g < 8; g++) accd += denss[g];
    }
  }

  float4* mp = (float4*)(msg + (size_t)n * 2048 + u * 16 + half * 8);
  mp[0] = make_float4(accm[0], accm[1], accm[2], accm[3]);
  mp[1] = make_float4(accm[4], accm[5], accm[6], accm[7]);
  *(float2*)(mmr + (size_t)n * 512 + u * 4 + half * 2) = make_float2(accmm0, accmm1);
  if (t == 0) densN[n] = accd;
}

// zero out2 blocks l=2,3 (no path -> zero)
__global__ void k_zero2(float* __restrict__ out2, int Nn) {
  int i = blockIdx.x * blockDim.x + threadIdx.x;
  if (i < Nn * 128) {
    float4 z = make_float4(0.f, 0.f, 0.f, 0.f);
    float4* p = (float4*)(out2 + (size_t)i * 16);
    p[1] = z;
    p[2] = z;
    p[3] = z;
  }
}

// ---------------- Wt pre-transpose (fp16) -----------------------------------
__global__ __launch_bounds__(128) void k_wt(const float* __restrict__ Wskip,
                                            const float* __restrict__ Wmskip,
                                            __half* __restrict__ Wt) {
  int bx = blockIdx.x;              // 0..767 : L = bx>>7, u = bx&127
  int L = bx >> 7, u = bx & 127;
  int v = threadIdx.x;
  const float* src = (L < 4) ? (Wskip + (size_t)L * 163840)
                             : (Wmskip + (size_t)(L - 4) * 163840);
  __half* dst = Wt + (((size_t)L * 128 + u) * 128 + v) * 12;
#pragma unroll
  for (int z = 0; z < 10; z++) dst[z] = __float2half(src[u * 1280 + z * 128 + v]);
  dst[10] = __float2half(0.f);
  dst[11] = __float2half(0.f);
}

// ---------------- merged per-l linear + skip TP, 8-node tiles ---------------
// v3: fdot2 z-dot (fp16 attrs x fp16 Wt, fp32 accum) + float4 LDS access with
// zero-padded SP slots.
template <int D, int SP>
__device__ __forceinline__ void skip2_body(
    const float* __restrict__ attrs, const float* __restrict__ in, int in_rs,
    int in_us, int in_cb, const float* __restrict__ Wl,
    const float* __restrict__ densN, float basescl, bool useDinv,
    const __half* __restrict__ Wt, float* __restrict__ outp, int out_cb,
    int Nn, int n0, float* lin_s, float (*attrs_s)[10]) {
  const int t = threadIdx.x;
  for (int i = t; i < 80; i += 256) {
    int nn = i / 10, z = i - nn * 10;
    int n = n0 + nn;
    attrs_s[nn][z] = (n < Nn) ? attrs[n * 10 + z] : 0.f;
  }
  // zero-padded staging: full SP per slot (pads = 0 so vector math is inert)
  for (int i = t; i < 8 * 128 * SP; i += 256) {
    int nn = i / (128 * SP);
    int r = i - nn * 128 * SP;
    int uu = r / SP;
    int m = r - uu * SP;
    int n = n0 + nn;
    lin_s[i] = (n < Nn && m < D) ? in[(size_t)n * in_rs + uu * in_us + in_cb + m] : 0.f;
  }
  __syncthreads();

  const int v = t & 127, hf = t >> 7;  // hf handles nodes hf*4+q, q=0..3
  constexpr int NV = (SP + 3) / 4;

  // ---- phase 1: per-l channel mix ----
  if constexpr (SP == 1) {
    float lm[4] = {0, 0, 0, 0};
    for (int uu = 0; uu < 128; uu++) {
      float wv = Wl[uu * 128 + v];
#pragma unroll
      for (int q = 0; q < 4; q++) lm[q] += lin_s[(hf * 4 + q) * 128 + uu] * wv;
    }
    __syncthreads();
#pragma unroll
    for (int q = 0; q < 4; q++) {
      int nd = n0 + hf * 4 + q;
      float scl = basescl;
      if (useDinv) scl *= 1.0f / (((nd < Nn) ? densN[nd] : 0.f) + 1.0f);
      lin_s[(hf * 4 + q) * 128 + v] = lm[q] * scl;
    }
    __syncthreads();
  } else {
    float4 lmv[4][NV];
#pragma unroll
    for (int q = 0; q < 4; q++)
#pragma unroll
      for (int iv = 0; iv < NV; iv++) lmv[q][iv] = make_float4(0.f, 0.f, 0.f, 0.f);
    for (int uu = 0; uu < 128; uu++) {
      float wv = Wl[uu * 128 + v];
#pragma unroll
      for (int q = 0; q < 4; q++) {
        const float4* ls4 = (const float4*)&lin_s[((hf * 4 + q) * 128 + uu) * SP];
#pragma unroll
        for (int iv = 0; iv < NV; iv++) {
          float4 lv = ls4[iv];
          lmv[q][iv].x += lv.x * wv;
          lmv[q][iv].y += lv.y * wv;
          lmv[q][iv].z += lv.z * wv;
          lmv[q][iv].w += lv.w * wv;
        }
      }
    }
    __syncthreads();
#pragma unroll
    for (int q = 0; q < 4; q++) {
      int nd = n0 + hf * 4 + q;
      float scl = basescl;
      if (useDinv) scl *= 1.0f / (((nd < Nn) ? densN[nd] : 0.f) + 1.0f);
      float4* d4 = (float4*)&lin_s[((hf * 4 + q) * 128 + v) * SP];
#pragma unroll
      for (int iv = 0; iv < NV; iv++) {
        float4 o = lmv[q][iv];
        o.x *= scl; o.y *= scl; o.z *= scl; o.w *= scl;
        d4[iv] = o;  // pads: 0*scl = 0
      }
    }
    __syncthreads();
  }

  // ---- phase 2: skip tensor product ----
  hv2 ah[4][5];
#pragma unroll
  for (int q = 0; q < 4; q++)
#pragma unroll
    for (int z2 = 0; z2 < 5; z2++) {
      hv2 a;
      a[0] = (_Float16)attrs_s[hf * 4 + q][2 * z2];
      a[1] = (_Float16)attrs_s[hf * 4 + q][2 * z2 + 1];
      ah[q][z2] = a;
    }

  const __half* wp0 = Wt + (size_t)v * 12;

  if constexpr (SP == 1) {
    float acc[4] = {0, 0, 0, 0};
    for (int u = 0; u < 128; u++) {
      const float2* fp = (const float2*)(wp0 + (size_t)u * 1536);
      float2 q0 = fp[0], q1 = fp[1], q2 = fp[2];
      FHV c0, c1, c2, c3, c4;
      c0.f = q0.x; c1.f = q0.y; c2.f = q1.x; c3.f = q1.y; c4.f = q2.x;
      hv2 wr[5] = {c0.h, c1.h, c2.h, c3.h, c4.h};
#pragma unroll
      for (int q = 0; q < 4; q++) {
        float wn = wn_dot(ah[q], wr);
        acc[q] += lin_s[(hf * 4 + q) * 128 + u] * wn;
      }
    }
#pragma unroll
    for (int q = 0; q < 4; q++) {
      int n = n0 + hf * 4 + q;
      if (n < Nn) outp[(size_t)n * 2048 + v * 16 + out_cb] = acc[q] * 0.027950849718747371f;
    }
  } else {
    float4 accv[4][NV];
#pragma unroll
    for (int q = 0; q < 4; q++)
#pragma unroll
      for (int iv = 0; iv < NV; iv++) accv[q][iv] = make_float4(0.f, 0.f, 0.f, 0.f);
    for (int u = 0; u < 128; u++) {
      const float2* fp = (const float2*)(wp0 + (size_t)u * 1536);
      float2 q0 = fp[0], q1 = fp[1], q2 = fp[2];
      FHV c0, c1, c2, c3, c4;
      c0.f = q0.x; c1.f = q0.y; c2.f = q1.x; c3.f = q1.y; c4.f = q2.x;
      hv2 wr[5] = {c0.h, c1.h, c2.h, c3.h, c4.h};
#pragma unroll
      for (int q = 0; q < 4; q++) {
        float wn = wn_dot(ah[q], wr);
        const float4* ls4 = (const float4*)&lin_s[((hf * 4 + q) * 128 + u) * SP];
#pragma unroll
        for (int iv = 0; iv < NV; iv++) {
          float4 lv = ls4[iv];
          accv[q][iv].x += lv.x * wn;
          accv[q][iv].y += lv.y * wn;
          accv[q][iv].z += lv.z * wn;
          accv[q][iv].w += lv.w * wn;
        }
      }
    }
#pragma unroll
    for (int q = 0; q < 4; q++) {
      int n = n0 + hf * 4 + q;
      if (n < Nn) {
        float* op = outp + (size_t)n * 2048 + v * 16 + out_cb;
        const float* af = (const float*)&accv[q][0];
#pragma unroll
        for (int m = 0; m < D; m++) op[m] = af[m] * 0.027950849718747371f;
      }
    }
  }
}

__global__ __launch_bounds__(256) void k_skip2(
    const float* __restrict__ attrs, const float* __restrict__ msg,
    const float* __restrict__ mmr, const float* __restrict__ densN,
    const float* __restrict__ Wlin, const float* __restrict__ Wmlin,
    const __half* __restrict__ Wt, float* __restrict__ out, int Nn) {
  __shared__ float lin_s[8 * 128 * 8];
  __shared__ float attrs_s[8][10];
  const int n0 = blockIdx.x * 8;
  const int job = blockIdx.y;
  const __half* Wtj = Wt + (size_t)job * 128 * 128 * 12;
  const float scl = 0.08838834764831845f;
  const float sm = 0.08838834764831845f / 20.0f;
  switch (job) {
    case 0: skip2_body<1, 1>(attrs, msg, 2048, 16, 0, Wlin, densN, scl, true, Wtj, out, 0, Nn, n0, lin_s, attrs_s); break;
    case 1: skip2_body<3, 4>(attrs, msg, 2048, 16, 1, Wlin + 16384, densN, scl, true, Wtj, out, 1, Nn, n0, lin_s, attrs_s); break;
    case 2: skip2_body<5, 8>(attrs, msg, 2048, 16, 4, Wlin + 32768, densN, scl, true, Wtj, out, 4, Nn, n0, lin_s, attrs_s); break;
    case 3: skip2_body<7, 8>(attrs, msg, 2048, 16, 9, Wlin + 49152, densN, scl, true, Wtj, out, 9, Nn, n0, lin_s, attrs_s); break;
    case 4: skip2_body<1, 1>(attrs, mmr, 512, 4, 0, Wmlin, densN, sm, false, Wtj, out + (size_t)Nn * 2048, 0, Nn, n0, lin_s, attrs_s); break;
    case 5: skip2_body<3, 4>(attrs, mmr, 512, 4, 1, Wmlin + 16384, densN, sm, false, Wtj, out + (size_t)Nn * 2048, 1, Nn, n0, lin_s, attrs_s); break;
  }
}

// ---------------- fallback: round-4 fused gather + old 16-node skip ---------
__global__ __launch_bounds__(256) void k_gather_f(
    const float* __restrict__ x, const float* __restrict__ edge_attrs,
    const float* __restrict__ edge_feats, const float* __restrict__ mminv,
    const float* __restrict__ mmattrs, const int* __restrict__ sender,
    const float* __restrict__ W1, const float* __restrict__ W2,
    const float* __restrict__ W3, const float* __restrict__ W4,
    const float* __restrict__ Mc, const float* __restrict__ Wd,
    const float* __restrict__ Wlin, const float* __restrict__ Wmlin,
    const int* __restrict__ rowstart, const int* __restrict__ elist,
    float* __restrict__ linm, float* __restrict__ linmm, int Nn) {
  const int n = blockIdx.x;
  const int t = threadIdx.x;
  const int start = rowstart[n], end = rowstart[n + 1];

  __shared__ float ef[8][16];
  __shared__ float hA[8][64];
  __shared__ float hB[8][64];
  __shared__ float ubuf[8 * 512 + 8 * 256];
  __shared__ float xjs[8][128];
  __shared__ float shs[8][16];
  __shared__ float mmshs[8][4];
  __shared__ float denss[8];
  __shared__ int eS[8], sS[8];
  __shared__ float dsum_s;

  float (*w4s)[512] = (float (*)[512])ubuf;
  float (*wmms)[256] = (float (*)[256])(ubuf + 8 * 512);
  float (*msg_s)[17] = (float (*)[17])ubuf;
  float (*mm_s)[5] = (float (*)[5])(ubuf + 128 * 17);

  float accm[8] = {0, 0, 0, 0, 0, 0, 0, 0};
  float accmm0 = 0.f, accmm1 = 0.f;
  float accd = 0.f;

  const int u = t & 127;
  const int half = t >> 7;
  const int gwave = t >> 6;
  const int o6 = t & 63;

  for (int base = start; base < end; base += 8) {
    if (t < 8) {
      int g = t;
      if (base + g < end) {
        int e = elist[base + g];
        eS[g] = e;
        sS[g] = sender[e];
      } else {
        eS[g] = -1;
        sS[g] = 0;
        denss[g] = 0.f;
      }
    }
    __syncthreads();
    if (t < 128) {
      int g = t >> 4, j = t & 15;
      int e = eS[g];
      shs[g][j] = (e >= 0) ? edge_attrs[e * 16 + j] : 0.f;
      float v = 0.f;
      if (e >= 0) v = (j < 8) ? edge_feats[e * 8 + j] : mminv[sS[g] * 8 + (j - 8)];
      ef[g][j] = v;
    } else if (t < 160) {
      int g = (t - 128) >> 2, j = (t - 128) & 3;
      mmshs[g][j] = (eS[g] >= 0) ? mmattrs[sS[g] * 4 + j] : 0.f;
    }
    for (int i = t; i < 1024; i += 256) {
      int g = i >> 7, uu = i & 127;
      xjs[g][uu] = (eS[g] >= 0) ? x[(size_t)sS[g] * 128 + uu] : 0.f;
    }
    if (t < 8 && eS[t] >= 0) {
      int e = eS[t];
      float q = 0.f;
#pragma unroll
      for (int k = 0; k < 8; k++) q += edge_feats[e * 8 + k] * Wd[k];
      q *= 0.35355339059327373f;
      denss[t] = tanhf(q * q);
    }
    __syncthreads();

#pragma unroll
    for (int rep = 0; rep < 2; rep++) {
      int g = gwave + rep * 4;
      float s = 0.f;
#pragma unroll
      for (int k = 0; k < 16; k++) s += ef[g][k] * W1[k * 64 + o6];
      hA[g][o6] = silu_f(s * 0.25f);
    }
#pragma unroll
    for (int rep = 0; rep < 2; rep++) {
      int g = gwave + rep * 4;
      float s = 0.f;
#pragma unroll 8
      for (int k = 0; k < 64; k++) s += hA[g][k] * W2[k * 64 + o6];
      hB[g][o6] = silu_f(s * 0.125f);
    }
#pragma unroll
    for (int rep = 0; rep < 2; rep++) {
      int g = gwave + rep * 4;
      float s = 0.f;
#pragma unroll 8
      for (int k = 0; k < 64; k++) s += hB[g][k] * W3[k * 64 + o6];
      hA[g][o6] = silu_f(s * 0.125f);
    }
    __syncthreads();
    {
      float a[8] = {0, 0, 0, 0, 0, 0, 0, 0};
      float b[8] = {0, 0, 0, 0, 0, 0, 0, 0};
#pragma unroll 8
      for (int k = 0; k < 64; k++) {
        float w0 = W4[k * 512 + t];
        float w1 = W4[k * 512 + t + 256];
#pragma unroll
        for (int g = 0; g < 8; g++) {
          float h = hA[g][k];
          a[g] += h * w0;
          b[g] += h * w1;
        }
      }
      int p0 = (t & 3) * 128 + (t >> 2);
      int p1 = (t & 3) * 128 + 64 + (t >> 2);
#pragma unroll
      for (int g = 0; g < 8; g++) {
        w4s[g][p0] = a[g] * 0.125f;
        w4s[g][p1] = b[g] * 0.125f;
      }
    }
    {
      float c[8] = {0, 0, 0, 0, 0, 0, 0, 0};
#pragma unroll
      for (int k = 0; k < 16; k++) {
        float w = Mc[k * 256 + t];
#pragma unroll
        for (int g = 0; g < 8; g++) c[g] += ef[g][k] * w;
      }
      int p = (t & 1) * 128 + (t >> 1);
#pragma unroll
      for (int g = 0; g < 8; g++) wmms[g][p] = c[g];
    }
    __syncthreads();
#pragma unroll 2
    for (int g = 0; g < 8; g++) {
      float xj = xjs[g][u];
      float sh0 = shs[g][0];
      float w40 = w4s[g][u];
      float w41 = w4s[g][128 + u];
      float w42 = w4s[g][256 + u];
      float w43 = w4s[g][384 + u];
      float pre0 = w40 * xj * sh0;
      float wg0 = wmms[g][u] * pre0;
      float wg1 = wmms[g][128 + u] * pre0;
      float mm0 = wg0 * xj * mmshs[g][0];
      float m1 = wg1 * xj;
      float bx = mm0 * xj;
      float b0 = w40 * bx, b1 = w41 * bx, b2 = w42 * bx, b3 = w43 * bx;
      if (half == 0) {
        accmm0 += mm0;
        accmm1 += m1 * mmshs[g][1];
        accm[0] += b0 * sh0;
        accm[1] += b1 * shs[g][1];
        accm[2] += b1 * shs[g][2];
        accm[3] += b1 * shs[g][3];
        accm[4] += b2 * shs[g][4];
        accm[5] += b2 * shs[g][5];
        accm[6] += b2 * shs[g][6];
        accm[7] += b2 * shs[g][7];
      } else {
        accmm0 += m1 * mmshs[g][2];
        accmm1 += m1 * mmshs[g][3];
        accm[0] += b2 * shs[g][8];
        accm[1] += b3 * shs[g][9];
        accm[2] += b3 * shs[g][10];
        accm[3] += b3 * shs[g][11];
        accm[4] += b3 * shs[g][12];
        accm[5] += b3 * shs[g][13];
        accm[6] += b3 * shs[g][14];
        accm[7] += b3 * shs[g][15];
      }
    }
    if (t == 0) {
#pragma unroll
      for (int g = 0; g < 8; g++) accd += denss[g];
    }
  }

  __syncthreads();
#pragma unroll
  for (int j = 0; j < 8; j++) msg_s[u][half * 8 + j] = accm[j];
  mm_s[u][half * 2 + 0] = accmm0;
  mm_s[u][half * 2 + 1] = accmm1;
  if (t == 0) dsum_s = accd;
  __syncthreads();
  const float dinv = 1.0f / (dsum_s + 1.0f);

  float outl[8] = {0, 0, 0, 0, 0, 0, 0, 0};
  if (half == 0) {
    for (int uu = 0; uu < 128; uu++) {
      float wl0 = Wlin[uu * 128 + u];
      float wl1 = Wlin[16384 + uu * 128 + u];
      float wl2 = Wlin[32768 + uu * 128 + u];
      outl[0] += msg_s[uu][0] * wl0;
      outl[1] += msg_s[uu][1] * wl1;
      outl[2] += msg_s[uu][2] * wl1;
      outl[3] += msg_s[uu][3] * wl1;
      outl[4] += msg_s[uu][4] * wl2;
      outl[5] += msg_s[uu][5] * wl2;
      outl[6] += msg_s[uu][6] * wl2;
      outl[7] += msg_s[uu][7] * wl2;
    }
  } else {
    for (int uu = 0; uu < 128; uu++) {
      float wl2 = Wlin[32768 + uu * 128 + u];
      float wl3 = Wlin[49152 + uu * 128 + u];
      outl[0] += msg_s[uu][8] * wl2;
      outl[1] += msg_s[uu][9] * wl3;
      outl[2] += msg_s[uu][10] * wl3;
      outl[3] += msg_s[uu][11] * wl3;
      outl[4] += msg_s[uu][12] * wl3;
      outl[5] += msg_s[uu][13] * wl3;
      outl[6] += msg_s[uu][14] * wl3;
      outl[7] += msg_s[uu][15] * wl3;
    }
  }
  const float sclv = 0.08838834764831845f * dinv;
  float4 v0 = make_float4(outl[0] * sclv, outl[1] * sclv, outl[2] * sclv, outl[3] * sclv);
  float4 v1 = make_float4(outl[4] * sclv, outl[5] * sclv, outl[6] * sclv, outl[7] * sclv);
  float4* lp = (float4*)(linm + (size_t)n * 2048 + u * 16 + half * 8);
  lp[0] = v0;
  lp[1] = v1;

  float om0 = 0.f, om1 = 0.f;
  if (half == 0) {
    for (int uu = 0; uu < 128; uu++) {
      om0 += mm_s[uu][0] * Wmlin[uu * 128 + u];
      om1 += mm_s[uu][1] * Wmlin[16384 + uu * 128 + u];
    }
  } else {
    for (int uu = 0; uu < 128; uu++) {
      float wm1 = Wmlin[16384 + uu * 128 + u];
      om0 += mm_s[uu][2] * wm1;
      om1 += mm_s[uu][3] * wm1;
    }
  }
  const float sm = 0.08838834764831845f / 20.0f;
  *(float2*)(linmm + (size_t)n * 512 + u * 4 + half * 2) = make_float2(om0 * sm, om1 * sm);
}

// old skip (fallback path), 16-node tiles, fp16 Wt
template <int D, int SP>
__device__ __forceinline__ void skip_body2(
    const float* __restrict__ attrs, const float* __restrict__ in, int in_rs,
    int in_us, int in_cb, const __half* __restrict__ Wt, float* __restrict__ outp,
    int out_cb, int Nn, int n0, float* lin_s, float (*attrs_s)[10]) {
  const int t = threadIdx.x;
  for (int i = t; i < 160; i += 256) {
    int nn = i / 10, z = i - nn * 10;
    int n = n0 + nn;
    attrs_s[nn][z] = (n < Nn) ? attrs[n * 10 + z] : 0.f;
  }
  for (int i = t; i < 16 * 128 * D; i += 256) {
    int nn = i / (128 * D);
    int r = i - nn * 128 * D;
    int uu = r / D;
    int m = r - uu * D;
    int n = n0 + nn;
    lin_s[(nn * 128 + uu) * SP + m] =
        (n < Nn) ? in[(size_t)n * in_rs + uu * in_us + in_cb + m] : 0.f;
  }
  __syncthreads();

  const int v = t & 127, hf = t >> 7;
  float ar[8][10];
#pragma unroll
  for (int q = 0; q < 8; q++)
#pragma unroll
    for (int z = 0; z < 10; z++) ar[q][z] = attrs_s[hf * 8 + q][z];

  float acc[8][D];
#pragma unroll
  for (int q = 0; q < 8; q++)
#pragma unroll
    for (int m = 0; m < D; m++) acc[q][m] = 0.f;

  const __half* wp0 = Wt + (size_t)v * 12;
  for (int u = 0; u < 128; u++) {
    const __half* wp = wp0 + (size_t)u * 1536;
    const float2* fp = (const float2*)wp;
    float2 q0 = fp[0];
    float2 q1 = fp[1];
    float2 q2 = fp[2];
    F2H2 c0, c1, c2, c3, c4;
    c0.f = q0.x; c1.f = q0.y; c2.f = q1.x; c3.f = q1.y; c4.f = q2.x;
    float wr[10];
    wr[0] = __low2float(c0.h); wr[1] = __high2float(c0.h);
    wr[2] = __low2float(c1.h); wr[3] = __high2float(c1.h);
    wr[4] = __low2float(c2.h); wr[5] = __high2float(c2.h);
    wr[6] = __low2float(c3.h); wr[7] = __high2float(c3.h);
    wr[8] = __low2float(c4.h); wr[9] = __high2float(c4.h);
#pragma unroll
    for (int q = 0; q < 8; q++) {
      float wn = 0.f;
#pragma unroll
      for (int z = 0; z < 10; z++) wn += ar[q][z] * wr[z];
      const float* ls = &lin_s[((hf * 8 + q) * 128 + u) * SP];
#pragma unroll
      for (int m = 0; m < D; m++) acc[q][m] += ls[m] * wn;
    }
  }
#pragma unroll
  for (int q = 0; q < 8; q++) {
    int n = n0 + hf * 8 + q;
    if (n < Nn) {
      float* op = outp + (size_t)n * 2048 + v * 16 + out_cb;
#pragma unroll
      for (int m = 0; m < D; m++) op[m] = acc[q][m] * 0.027950849718747371f;
    }
  }
}

__global__ __launch_bounds__(256) void k_skip(
    const float* __restrict__ attrs, const float* __restrict__ linm,
    const float* __restrict__ linmm, const __half* __restrict__ Wt,
    float* __restrict__ out, int Nn) {
  __shared__ float lin_s[16 * 128 * 8];
  __shared__ float attrs_s[16][10];
  const int n0 = blockIdx.x * 16;
  const int job = blockIdx.y;
  const __half* Wtj = Wt + (size_t)job * 128 * 128 * 12;
  switch (job) {
    case 0: skip_body2<1, 1>(attrs, linm, 2048, 16, 0, Wtj, out, 0, Nn, n0, lin_s, attrs_s); break;
    case 1: skip_body2<3, 4>(attrs, linm, 2048, 16, 1, Wtj, out, 1, Nn, n0, lin_s, attrs_s); break;
    case 2: skip_body2<5, 8>(attrs, linm, 2048, 16, 4, Wtj, out, 4, Nn, n0, lin_s, attrs_s); break;
    case 3: skip_body2<7, 8>(attrs, linm, 2048, 16, 9, Wtj, out, 9, Nn, n0, lin_s, attrs_s); break;
    case 4: skip_body2<1, 1>(attrs, linmm, 512, 4, 0, Wtj, out + (size_t)Nn * 2048, 0, Nn, n0, lin_s, attrs_s); break;
    case 5: skip_body2<3, 4>(attrs, linmm, 512, 4, 1, Wtj, out + (size_t)Nn * 2048, 1, Nn, n0, lin_s, attrs_s); break;
  }
}

extern "C" void kernel_launch(void* const* d_in, const int* in_sizes, int n_in,
                              void* d_out, int out_size, void* d_ws, size_t ws_size,
                              hipStream_t stream) {
  const float* node_attrs = (const float*)d_in[0];
  const float* node_feats = (const float*)d_in[1];
  const float* edge_attrs = (const float*)d_in[2];
  const float* edge_feats = (const float*)d_in[3];
  const float* mminv = (const float*)d_in[4];
  const float* mmattrs = (const float*)d_in[5];
  const int* edge_index = (const int*)d_in[6];
  const float* W_up = (const float*)d_in[7];
  const float* W1 = (const float*)d_in[8];
  const float* W2 = (const float*)d_in[9];
  const float* W3 = (const float*)d_in[10];
  const float* W4 = (const float*)d_in[11];
  const float* M1 = (const float*)d_in[12];
  const float* M2 = (const float*)d_in[13];
  const float* M3 = (const float*)d_in[14];
  const float* M4 = (const float*)d_in[15];
  const float* Wd = (const float*)d_in[16];
  const float* Wlin = (const float*)d_in[17];
  const float* Wmlin = (const float*)d_in[18];
  const float* Wskip = (const float*)d_in[19];
  const float* Wmskip = (const float*)d_in[20];

  const int N = in_sizes[1] / 128;
  const int E = in_sizes[2] / 16;
  const int* sender = edge_index;
  const int* recv = edge_index + E;

  float* ws = (float*)d_ws;
  float* x = ws;     ws += (size_t)N * 128;
  float* Mc = ws;    ws += 16 * 256;
  __half* Wt = (__half*)ws;  ws += (size_t)6 * 128 * 128 * 12 / 2;  // fp16
  __half2* W4h = (__half2*)ws; ws += 64 * 256;                      // 1 word per half2
  float* msg = ws;   ws += (size_t)N * 2048;   // fallback: linm
  float* mmr = ws;   ws += (size_t)N * 512;    // fallback: linmm
  float* densN = ws; ws += N;
  float* dens = ws;  ws += E;
  int* ibuf = (int*)ws;
  int* rowstart = ibuf;            // N+1
  int* deg = ibuf + (N + 1);       // N
  int* cursor = deg + N;           // N
  int* elist = cursor + N;         // E
  char* tail = (char*)(((uintptr_t)(elist + E) + 63) & ~(uintptr_t)63);
  size_t tailOff = (size_t)(tail - (char*)d_ws);
  size_t needA = tailOff + (size_t)E * 512 * 2 + 256;  // w4e half, ~160 MB
  size_t needB = tailOff + (size_t)E * 64 * 4 + 256;   // hAe fp32, ~83 MB
  __half* w4e = (__half*)tail;   // mode A
  float* hAe = (float*)tail;     // mode B (union; modes exclusive)
  const int mode = (ws_size >= needA) ? 0 : (ws_size >= needB ? 1 : 2);

  k_zero_int<<<(N + 255) / 256, 256, 0, stream>>>(deg, N);
  k_prep<<<1, 256, 0, stream>>>(M1, M2, M3, M4, Mc);
  k_wt<<<768, 128, 0, stream>>>(Wskip, Wmskip, Wt);
  k_up<<<N, 128, 0, stream>>>(node_feats, W_up, x, N);
  k_count<<<(E + 255) / 256, 256, 0, stream>>>(recv, deg, E);
  k_scan<<<1, 1024, 0, stream>>>(deg, rowstart, cursor, N);
  k_fill<<<(E + 255) / 256, 256, 0, stream>>>(recv, cursor, elist, E);

  if (mode == 0) {
    k_edge_w4<<<(E + 7) / 8, 256, 0, stream>>>(edge_feats, mminv, sender, W1,
                                               W2, W3, W4, Wd, w4e, dens, E);
    k_gather_c<<<N, 256, 0, stream>>>(x, edge_attrs, edge_feats, mminv,
                                      mmattrs, sender, Mc, w4e, dens, rowstart,
                                      elist, msg, mmr, densN, N);
    k_zero2<<<(N * 128 + 255) / 256, 256, 0, stream>>>((float*)d_out + (size_t)N * 2048, N);
    dim3 gs2((N + 7) / 8, 6);
    k_skip2<<<gs2, 256, 0, stream>>>(node_attrs, msg, mmr, densN, Wlin, Wmlin,
                                     Wt, (float*)d_out, N);
  } else if (mode == 1) {
    k_w4h<<<64, 256, 0, stream>>>(W4, W4h);
    k_edge_hA<<<(E + 7) / 8, 256, 0, stream>>>(edge_feats, mminv, sender, W1,
                                               W2, W3, Wd, hAe, dens, E);
    k_gather_raw<<<N, 256, 0, stream>>>(x, edge_attrs, edge_feats, mminv,
                                        mmattrs, sender, W4h, Mc, dens, hAe,
                                        rowstart, elist, msg, mmr, densN, N);
    k_zero2<<<(N * 128 + 255) / 256, 256, 0, stream>>>((float*)d_out + (size_t)N * 2048, N);
    dim3 gs2((N + 7) / 8, 6);
    k_skip2<<<gs2, 256, 0, stream>>>(node_attrs, msg, mmr, densN, Wlin, Wmlin,
                                     Wt, (float*)d_out, N);
  } else {
    k_gather_f<<<N, 256, 0, stream>>>(x, edge_attrs, edge_feats, mminv,
                                      mmattrs, sender, W1, W2, W3, W4, Mc, Wd,
                                      Wlin, Wmlin, rowstart, elist, msg, mmr, N);
    k_zero2<<<(N * 128 + 255) / 256, 256, 0, stream>>>((float*)d_out + (size_t)N * 2048, N);
    dim3 gs((N + 15) / 16, 6);
    k_skip<<<gs, 256, 0, stream>>>(node_attrs, msg, mmr, Wt, (float*)d_out, N);
  }
}